// Round 2
// baseline (2886.284 us; speedup 1.0000x reference)
//
#include <hip/hip_runtime.h>
#include <hip/hip_bf16.h>

#define HW 112
#define NPIX (HW*HW)            // 12544
#define NTOK_TOTAL (16*NPIX)    // 200704
#define SCALE_ATTN 0.17677669529663689f

__device__ __forceinline__ float gelu_exact(float x) {
    return 0.5f * x * (1.0f + erff(x * 0.70710678118654752f));
}

__device__ __forceinline__ float dot4(float4 a, float4 b, float acc) {
    acc = fmaf(a.x, b.x, acc); acc = fmaf(a.y, b.y, acc);
    acc = fmaf(a.z, b.z, acc); acc = fmaf(a.w, b.w, acc);
    return acc;
}

// ---------------- patch merging: x (16,3,448,448) -> xp (16,112,112,96) ----
__global__ __launch_bounds__(256) void patch_merge_kernel(
    const float* __restrict__ x, const float* __restrict__ pm_w,
    const float* __restrict__ pm_b, float* __restrict__ xp)
{
    __shared__ float w_lds[48*96];
    __shared__ float in_lds[16*52];
    __shared__ float b_lds[96];
    const int t = threadIdx.x;
    const int jt = blockIdx.x, i = blockIdx.y, b = blockIdx.z;
    const int j0 = jt * 16;

    for (int e = t; e < 48*96; e += 256) w_lds[e] = pm_w[e];
    if (t < 96) b_lds[t] = pm_b[t];
    for (int e = t; e < 768; e += 256) {
        int r = e >> 6, col = e & 63;
        int c = r >> 2, kh = r & 3;
        float v = x[(((size_t)(b*3 + c))*448 + (4*i + kh))*448 + 4*j0 + col];
        in_lds[(col >> 2)*52 + c*16 + kh*4 + (col & 3)] = v;
    }
    __syncthreads();
    for (int e = t; e < 16*96; e += 256) {
        int pos = e / 96, ch = e % 96;
        float acc = b_lds[ch];
        #pragma unroll
        for (int k = 0; k < 48; ++k)
            acc = fmaf(in_lds[pos*52 + k], w_lds[k*96 + ch], acc);
        xp[((size_t)((b*HW + i)*HW) + j0 + pos)*96 + ch] = acc;
    }
}

// ------------- fused LN1 + qkv(head slice) + windowed attention ------------
// one block per (window, head, batch); writes o_buf (b,112,112,96)
template<bool SHIFTED>
__global__ __launch_bounds__(256) void attn_kernel(
    const float* __restrict__ xp, const float* __restrict__ ln_g,
    const float* __restrict__ ln_b, const float* __restrict__ qkv_w,
    const float* __restrict__ pos_tab, float* __restrict__ o_buf)
{
    __shared__ float ybuf[49*100];   // LN'd tile; later aliased as dots[49][52]
    __shared__ float wT[96*100];     // qkv weight slice transposed [c][k]
    __shared__ float qkv[49*100];    // q|k|v per token (32 each)
    __shared__ float pos_l[169];
    __shared__ float stat[49*2];
    __shared__ float lng[96], lnb[96];

    const int t = threadIdx.x;
    const int wh = blockIdx.x >> 4, ww = blockIdx.x & 15;
    const int h = blockIdx.y, b = blockIdx.z;
    const int SH = SHIFTED ? 3 : 0;

    // stage xp rows of this window (shift folded into the gather)
    for (int e = t; e < 49*24; e += 256) {
        int tok = e / 24, p = e % 24;
        int ti = tok / 7, tj = tok % 7;
        int gi = wh*7 + ti + SH; if (gi >= HW) gi -= HW;
        int gj = ww*7 + tj + SH; if (gj >= HW) gj -= HW;
        const float4 v = *reinterpret_cast<const float4*>(
            xp + ((size_t)((b*HW + gi)*HW + gj))*96 + p*4);
        *reinterpret_cast<float4*>(&ybuf[tok*100 + p*4]) = v;
    }
    if (t < 96) { lng[t] = ln_g[t]; lnb[t] = ln_b[t]; }
    for (int e = t; e < 169; e += 256) pos_l[e] = pos_tab[e];
    // transposed load of this head's 96x96 qkv-weight slice
    for (int e = t; e < 96*96; e += 256) {
        int k = e / 96, c = e % 96;
        int col = (c >> 5)*96 + h*32 + (c & 31);
        wT[c*100 + k] = qkv_w[k*288 + col];
    }
    __syncthreads();

    // LN stats per token
    if (t < 49) {
        float s = 0.f, s2 = 0.f;
        for (int k = 0; k < 96; ++k) { float v = ybuf[t*100+k]; s += v; s2 += v*v; }
        float mu = s * (1.f/96.f);
        float var = s2 * (1.f/96.f) - mu*mu;
        stat[t*2] = mu; stat[t*2+1] = rsqrtf(var + 1e-5f);
    }
    __syncthreads();
    for (int e = t; e < 49*96; e += 256) {
        int tok = e / 96, k = e % 96;
        ybuf[tok*100+k] = (ybuf[tok*100+k] - stat[tok*2]) * stat[tok*2+1] * lng[k] + lnb[k];
    }
    __syncthreads();

    // qkv = y @ wT : each thread 3 cols (q,k,v) x up-to-7 tokens
    {
        const int cg = t & 31, tg = t >> 5;
        float a0[7], a1[7], a2[7];
        #pragma unroll
        for (int i2 = 0; i2 < 7; ++i2) { a0[i2]=0.f; a1[i2]=0.f; a2[i2]=0.f; }
        for (int k = 0; k < 96; k += 4) {
            const float4 w0 = *reinterpret_cast<const float4*>(&wT[cg*100 + k]);
            const float4 w1 = *reinterpret_cast<const float4*>(&wT[(cg+32)*100 + k]);
            const float4 w2 = *reinterpret_cast<const float4*>(&wT[(cg+64)*100 + k]);
            #pragma unroll
            for (int i2 = 0; i2 < 7; ++i2) {
                int tok = tg + 8*i2; tok = tok < 49 ? tok : 48;
                const float4 y4 = *reinterpret_cast<const float4*>(&ybuf[tok*100 + k]);
                a0[i2] = dot4(y4, w0, a0[i2]);
                a1[i2] = dot4(y4, w1, a1[i2]);
                a2[i2] = dot4(y4, w2, a2[i2]);
            }
        }
        #pragma unroll
        for (int i2 = 0; i2 < 7; ++i2) {
            int tok = tg + 8*i2;
            if (tok < 49) {
                qkv[tok*100 + cg]      = a0[i2];
                qkv[tok*100 + cg + 32] = a1[i2];
                qkv[tok*100 + cg + 64] = a2[i2];
            }
        }
    }
    __syncthreads();

    // dots = q k^T * scale + pos_bias (+ shift mask); aliases ybuf
    for (int e = t; e < 49*49; e += 256) {
        int i2 = e / 49, j = e % 49;
        float acc = 0.f;
        #pragma unroll
        for (int k = 0; k < 32; k += 4) {
            const float4 q4 = *reinterpret_cast<const float4*>(&qkv[i2*100 + k]);
            const float4 k4 = *reinterpret_cast<const float4*>(&qkv[j*100 + 32 + k]);
            acc = dot4(q4, k4, acc);
        }
        acc *= SCALE_ATTN;
        int xi = i2 / 7, yi = i2 % 7, xj = j / 7, yj = j % 7;
        acc += pos_l[(xj - xi + 6)*13 + (yj - yi + 6)];
        if (SHIFTED) {
            if (wh == 15 && ((xi >= 4) != (xj >= 4))) acc = -1e30f;
            if (ww == 15 && ((yi >= 4) != (yj >= 4))) acc = -1e30f;
        }
        ybuf[i2*52 + j] = acc;
    }
    __syncthreads();

    // softmax per row
    if (t < 49) {
        float m = -1e30f;
        for (int j = 0; j < 49; ++j) m = fmaxf(m, ybuf[t*52 + j]);
        float s = 0.f;
        for (int j = 0; j < 49; ++j) {
            float ev = __expf(ybuf[t*52 + j] - m);
            ybuf[t*52 + j] = ev; s += ev;
        }
        float inv = 1.f / s;
        for (int j = 0; j < 49; ++j) ybuf[t*52 + j] *= inv;
    }
    __syncthreads();

    // o = attn @ v, scatter back with inverse shift (same index mapping)
    for (int e = t; e < 49*32; e += 256) {
        int tok = e >> 5, d = e & 31;
        float acc = 0.f;
        for (int j = 0; j < 49; ++j)
            acc = fmaf(ybuf[tok*52 + j], qkv[j*100 + 64 + d], acc);
        int ti = tok / 7, tj = tok % 7;
        int gi = wh*7 + ti + SH; if (gi >= HW) gi -= HW;
        int gj = ww*7 + tj + SH; if (gj >= HW) gj -= HW;
        o_buf[((size_t)((b*HW + gi)*HW + gj))*96 + h*32 + d] = acc;
    }
}

// ----------------- out-proj + residual: xp += o @ W + b --------------------
__global__ __launch_bounds__(256) void proj_kernel(
    const float* __restrict__ o_buf, const float* __restrict__ w,
    const float* __restrict__ bias, float* __restrict__ xp)
{
    __shared__ float o_t[64*100];
    __shared__ float wT[96*100];
    __shared__ float bs[96];
    const int t = threadIdx.x;
    const size_t tok0 = (size_t)blockIdx.x * 64;

    for (int e = t; e < 64*24; e += 256) {
        int r = e / 24, p = e % 24;
        *reinterpret_cast<float4*>(&o_t[r*100 + p*4]) =
            *reinterpret_cast<const float4*>(o_buf + (tok0 + r)*96 + p*4);
    }
    for (int e = t; e < 96*96; e += 256) {
        int k = e / 96, n = e % 96;
        wT[n*100 + k] = w[k*96 + n];
    }
    if (t < 96) bs[t] = bias[t];
    __syncthreads();

    const int cg = t & 31, tg = t >> 5;
    float a0[8], a1[8], a2[8];
    #pragma unroll
    for (int i = 0; i < 8; ++i) { a0[i]=0.f; a1[i]=0.f; a2[i]=0.f; }
    for (int k = 0; k < 96; k += 4) {
        const float4 w0 = *reinterpret_cast<const float4*>(&wT[cg*100 + k]);
        const float4 w1 = *reinterpret_cast<const float4*>(&wT[(cg+32)*100 + k]);
        const float4 w2 = *reinterpret_cast<const float4*>(&wT[(cg+64)*100 + k]);
        #pragma unroll
        for (int i = 0; i < 8; ++i) {
            const float4 y4 = *reinterpret_cast<const float4*>(&o_t[(tg*8+i)*100 + k]);
            a0[i] = dot4(y4, w0, a0[i]);
            a1[i] = dot4(y4, w1, a1[i]);
            a2[i] = dot4(y4, w2, a2[i]);
        }
    }
    #pragma unroll
    for (int i = 0; i < 8; ++i) {
        size_t g = (tok0 + tg*8 + i)*96;
        xp[g + cg]      += a0[i] + bs[cg];
        xp[g + cg + 32] += a1[i] + bs[cg + 32];
        xp[g + cg + 64] += a2[i] + bs[cg + 64];
    }
}

// ------------- fused LN2 + FF1 + GELU + FF2 + residual ---------------------
__global__ __launch_bounds__(256) void ff_kernel(
    float* __restrict__ xp, const float* __restrict__ ln_g,
    const float* __restrict__ ln_b, const float* __restrict__ w1,
    const float* __restrict__ b1, const float* __restrict__ w2,
    const float* __restrict__ b2)
{
    __shared__ float y_t[64*100];
    __shared__ float h_t[64*100];
    __shared__ float wT[96*100];
    __shared__ float stat[64*2];
    __shared__ float lg[96], lb[96];
    const int t = threadIdx.x;
    const size_t tok0 = (size_t)blockIdx.x * 64;

    for (int e = t; e < 64*24; e += 256) {
        int r = e / 24, p = e % 24;
        *reinterpret_cast<float4*>(&y_t[r*100 + p*4]) =
            *reinterpret_cast<const float4*>(xp + (tok0 + r)*96 + p*4);
    }
    if (t < 96) { lg[t] = ln_g[t]; lb[t] = ln_b[t]; }
    __syncthreads();
    if (t < 64) {
        float s = 0.f, s2 = 0.f;
        for (int k = 0; k < 96; ++k) { float v = y_t[t*100+k]; s += v; s2 += v*v; }
        float mu = s*(1.f/96.f);
        float var = s2*(1.f/96.f) - mu*mu;
        stat[t*2] = mu; stat[t*2+1] = rsqrtf(var + 1e-5f);
    }
    __syncthreads();
    for (int e = t; e < 64*96; e += 256) {
        int r = e / 96, k = e % 96;
        y_t[r*100+k] = (y_t[r*100+k] - stat[r*2]) * stat[r*2+1] * lg[k] + lb[k];
    }

    const int cg = t & 31, tg = t >> 5;
    float a0[8], a1[8], a2[8];
    #pragma unroll
    for (int i = 0; i < 8; ++i) { a0[i]=0.f; a1[i]=0.f; a2[i]=0.f; }

    for (int c = 0; c < 4; ++c) {
        __syncthreads();   // y ready / prev chunk done with wT & h_t
        for (int e = t; e < 96*96; e += 256) {
            int k = e / 96, n = e % 96;
            wT[n*100 + k] = w1[k*384 + c*96 + n];
        }
        __syncthreads();
        float h0[8], h1[8], h2[8];
        #pragma unroll
        for (int i = 0; i < 8; ++i) { h0[i]=0.f; h1[i]=0.f; h2[i]=0.f; }
        for (int k = 0; k < 96; k += 4) {
            const float4 w0 = *reinterpret_cast<const float4*>(&wT[cg*100 + k]);
            const float4 w1v = *reinterpret_cast<const float4*>(&wT[(cg+32)*100 + k]);
            const float4 w2v = *reinterpret_cast<const float4*>(&wT[(cg+64)*100 + k]);
            #pragma unroll
            for (int i = 0; i < 8; ++i) {
                const float4 y4 = *reinterpret_cast<const float4*>(&y_t[(tg*8+i)*100 + k]);
                h0[i] = dot4(y4, w0, h0[i]);
                h1[i] = dot4(y4, w1v, h1[i]);
                h2[i] = dot4(y4, w2v, h2[i]);
            }
        }
        float bb0 = b1[c*96 + cg], bb1 = b1[c*96 + cg + 32], bb2 = b1[c*96 + cg + 64];
        #pragma unroll
        for (int i = 0; i < 8; ++i) {
            int r = tg*8 + i;
            h_t[r*100 + cg]      = gelu_exact(h0[i] + bb0);
            h_t[r*100 + cg + 32] = gelu_exact(h1[i] + bb1);
            h_t[r*100 + cg + 64] = gelu_exact(h2[i] + bb2);
        }
        __syncthreads();
        for (int e = t; e < 96*96; e += 256) {
            int k = e / 96, n = e % 96;
            wT[n*100 + k] = w2[(size_t)(c*96 + k)*96 + n];
        }
        __syncthreads();
        for (int k = 0; k < 96; k += 4) {
            const float4 w0 = *reinterpret_cast<const float4*>(&wT[cg*100 + k]);
            const float4 w1v = *reinterpret_cast<const float4*>(&wT[(cg+32)*100 + k]);
            const float4 w2v = *reinterpret_cast<const float4*>(&wT[(cg+64)*100 + k]);
            #pragma unroll
            for (int i = 0; i < 8; ++i) {
                const float4 h4 = *reinterpret_cast<const float4*>(&h_t[(tg*8+i)*100 + k]);
                a0[i] = dot4(h4, w0, a0[i]);
                a1[i] = dot4(h4, w1v, a1[i]);
                a2[i] = dot4(h4, w2v, a2[i]);
            }
        }
    }
    #pragma unroll
    for (int i = 0; i < 8; ++i) {
        size_t g = (tok0 + tg*8 + i)*96;
        xp[g + cg]      += a0[i] + b2[cg];
        xp[g + cg + 32] += a1[i] + b2[cg + 32];
        xp[g + cg + 64] += a2[i] + b2[cg + 64];
    }
}

// ------------- (b,112,112,96) -> (b,96,112,112) fp32 -----------------------
__global__ __launch_bounds__(256) void out_kernel(
    const float* __restrict__ xp, float* __restrict__ out)
{
    __shared__ float tile[64*100];
    const int t = threadIdx.x;
    const int b = blockIdx.y;
    const int p0 = blockIdx.x * 64;
    for (int e = t; e < 64*24; e += 256) {
        int r = e / 24, p = e % 24;
        *reinterpret_cast<float4*>(&tile[r*100 + p*4]) =
            *reinterpret_cast<const float4*>(xp + ((size_t)b*NPIX + p0 + r)*96 + p*4);
    }
    __syncthreads();
    for (int e = t; e < 96*64; e += 256) {
        int ch = e >> 6, p = e & 63;
        out[((size_t)(b*96 + ch))*NPIX + p0 + p] = tile[p*100 + ch];
    }
}

extern "C" void kernel_launch(void* const* d_in, const int* in_sizes, int n_in,
                              void* d_out, int out_size, void* d_ws, size_t ws_size,
                              hipStream_t stream)
{
    (void)in_sizes; (void)n_in; (void)out_size; (void)ws_size;
    const float* x     = (const float*)d_in[0];
    const float* pm_w  = (const float*)d_in[1];
    const float* pm_b  = (const float*)d_in[2];
    const float* ln1_g = (const float*)d_in[3];
    const float* ln1_b = (const float*)d_in[4];
    const float* qkv_w = (const float*)d_in[5];
    const float* pos   = (const float*)d_in[6];
    const float* out_w = (const float*)d_in[7];
    const float* out_b = (const float*)d_in[8];
    const float* ln2_g = (const float*)d_in[9];
    const float* ln2_b = (const float*)d_in[10];
    const float* ff1_w = (const float*)d_in[11];
    const float* ff1_b = (const float*)d_in[12];
    const float* ff2_w = (const float*)d_in[13];
    const float* ff2_b = (const float*)d_in[14];

    float* xp    = (float*)d_ws;
    float* o_buf = xp + (size_t)NTOK_TOTAL * 96;

    patch_merge_kernel<<<dim3(7, 112, 16), 256, 0, stream>>>(x, pm_w, pm_b, xp);

    for (int L = 0; L < 2; ++L) {
        const float* qw = qkv_w + (size_t)L*96*288;
        const float* pt = pos + L*169;
        if (L == 0)
            attn_kernel<false><<<dim3(256,3,16), 256, 0, stream>>>(
                xp, ln1_g + L*96, ln1_b + L*96, qw, pt, o_buf);
        else
            attn_kernel<true><<<dim3(256,3,16), 256, 0, stream>>>(
                xp, ln1_g + L*96, ln1_b + L*96, qw, pt, o_buf);
        proj_kernel<<<3136, 256, 0, stream>>>(
            o_buf, out_w + (size_t)L*96*96, out_b + L*96, xp);
        ff_kernel<<<3136, 256, 0, stream>>>(
            xp, ln2_g + L*96, ln2_b + L*96,
            ff1_w + (size_t)L*96*384, ff1_b + L*384,
            ff2_w + (size_t)L*384*96, ff2_b + L*96);
    }
    out_kernel<<<dim3(196, 16), 256, 0, stream>>>(xp, (float*)d_out);
}

// Round 3
// 1543.415 us; speedup vs baseline: 1.8701x; 1.8701x over previous
//
#include <hip/hip_runtime.h>
#include <hip/hip_bf16.h>

#define HW 112
#define NPIX (HW*HW)            // 12544
#define NTOK_TOTAL (16*NPIX)    // 200704
#define SCALE_ATTN 0.17677669529663689f

typedef short bf16x8 __attribute__((ext_vector_type(8)));
typedef float f32x4 __attribute__((ext_vector_type(4)));

__device__ __forceinline__ float dot4(float4 a, float4 b, float acc) {
    acc = fmaf(a.x, b.x, acc); acc = fmaf(a.y, b.y, acc);
    acc = fmaf(a.z, b.z, acc); acc = fmaf(a.w, b.w, acc);
    return acc;
}

__device__ __forceinline__ short f2bf(float f) {
    __hip_bfloat16 h = __float2bfloat16(f);
    return *reinterpret_cast<short*>(&h);
}

// fast erf-based GELU (Abramowitz-Stegun 7.1.26, |err| < 1.5e-7)
__device__ __forceinline__ float gelu_fast(float x) {
    float s = x * 0.70710678118654752f;
    float a = fabsf(s);
    float t = __builtin_amdgcn_rcpf(1.0f + 0.3275911f * a);
    float p = t*(0.254829592f + t*(-0.284496736f + t*(1.421413741f
              + t*(-1.453152027f + t*1.061405429f))));
    float e = __expf(-a * a);
    float erf_a = 1.0f - p * e;
    float erf_s = s < 0.f ? -erf_a : erf_a;
    return 0.5f * x * (1.0f + erf_s);
}

// ---------------- patch merging: x (16,3,448,448) -> xp (16,112,112,96) ----
__global__ __launch_bounds__(256) void patch_merge_kernel(
    const float* __restrict__ x, const float* __restrict__ pm_w,
    const float* __restrict__ pm_b, float* __restrict__ xp)
{
    __shared__ float w_lds[48*96];
    __shared__ float in_lds[16*52];
    __shared__ float b_lds[96];
    const int t = threadIdx.x;
    const int jt = blockIdx.x, i = blockIdx.y, b = blockIdx.z;
    const int j0 = jt * 16;

    for (int e = t; e < 48*96; e += 256) w_lds[e] = pm_w[e];
    if (t < 96) b_lds[t] = pm_b[t];
    for (int e = t; e < 768; e += 256) {
        int r = e >> 6, col = e & 63;
        int c = r >> 2, kh = r & 3;
        float v = x[(((size_t)(b*3 + c))*448 + (4*i + kh))*448 + 4*j0 + col];
        in_lds[(col >> 2)*52 + c*16 + kh*4 + (col & 3)] = v;
    }
    __syncthreads();
    for (int e = t; e < 16*96; e += 256) {
        int pos = e / 96, ch = e % 96;
        float acc = b_lds[ch];
        #pragma unroll
        for (int k = 0; k < 48; ++k)
            acc = fmaf(in_lds[pos*52 + k], w_lds[k*96 + ch], acc);
        xp[((size_t)((b*HW + i)*HW) + j0 + pos)*96 + ch] = acc;
    }
}

// ------------- fused LN1 + qkv(head slice) + windowed attention ------------
template<bool SHIFTED>
__global__ __launch_bounds__(256) void attn_kernel(
    const float* __restrict__ xp, const float* __restrict__ ln_g,
    const float* __restrict__ ln_b, const float* __restrict__ qkv_w,
    const float* __restrict__ pos_tab, float* __restrict__ o_buf)
{
    __shared__ float ybuf[49*100];   // LN'd tile; later aliased as dots[49][52]
    __shared__ float wT[96*100];     // qkv weight slice transposed [c][k]
    __shared__ float qkv[49*100];    // q|k|v per token (32 each)
    __shared__ float pos_l[169];
    __shared__ float stat[49*2];
    __shared__ float lng[96], lnb[96];

    const int t = threadIdx.x;
    const int wh = blockIdx.x >> 4, ww = blockIdx.x & 15;
    const int h = blockIdx.y, b = blockIdx.z;
    const int SH = SHIFTED ? 3 : 0;

    for (int e = t; e < 49*24; e += 256) {
        int tok = e / 24, p = e % 24;
        int ti = tok / 7, tj = tok % 7;
        int gi = wh*7 + ti + SH; if (gi >= HW) gi -= HW;
        int gj = ww*7 + tj + SH; if (gj >= HW) gj -= HW;
        const float4 v = *reinterpret_cast<const float4*>(
            xp + ((size_t)((b*HW + gi)*HW + gj))*96 + p*4);
        *reinterpret_cast<float4*>(&ybuf[tok*100 + p*4]) = v;
    }
    if (t < 96) { lng[t] = ln_g[t]; lnb[t] = ln_b[t]; }
    for (int e = t; e < 169; e += 256) pos_l[e] = pos_tab[e];
    for (int e = t; e < 96*96; e += 256) {
        int k = e / 96, c = e % 96;
        int col = (c >> 5)*96 + h*32 + (c & 31);
        wT[c*100 + k] = qkv_w[k*288 + col];
    }
    __syncthreads();

    if (t < 49) {
        float s = 0.f, s2 = 0.f;
        for (int k = 0; k < 96; ++k) { float v = ybuf[t*100+k]; s += v; s2 += v*v; }
        float mu = s * (1.f/96.f);
        float var = s2 * (1.f/96.f) - mu*mu;
        stat[t*2] = mu; stat[t*2+1] = rsqrtf(var + 1e-5f);
    }
    __syncthreads();
    for (int e = t; e < 49*96; e += 256) {
        int tok = e / 96, k = e % 96;
        ybuf[tok*100+k] = (ybuf[tok*100+k] - stat[tok*2]) * stat[tok*2+1] * lng[k] + lnb[k];
    }
    __syncthreads();

    {
        const int cg = t & 31, tg = t >> 5;
        float a0[7], a1[7], a2[7];
        #pragma unroll
        for (int i2 = 0; i2 < 7; ++i2) { a0[i2]=0.f; a1[i2]=0.f; a2[i2]=0.f; }
        for (int k = 0; k < 96; k += 4) {
            const float4 w0 = *reinterpret_cast<const float4*>(&wT[cg*100 + k]);
            const float4 w1 = *reinterpret_cast<const float4*>(&wT[(cg+32)*100 + k]);
            const float4 w2 = *reinterpret_cast<const float4*>(&wT[(cg+64)*100 + k]);
            #pragma unroll
            for (int i2 = 0; i2 < 7; ++i2) {
                int tok = tg + 8*i2; tok = tok < 49 ? tok : 48;
                const float4 y4 = *reinterpret_cast<const float4*>(&ybuf[tok*100 + k]);
                a0[i2] = dot4(y4, w0, a0[i2]);
                a1[i2] = dot4(y4, w1, a1[i2]);
                a2[i2] = dot4(y4, w2, a2[i2]);
            }
        }
        #pragma unroll
        for (int i2 = 0; i2 < 7; ++i2) {
            int tok = tg + 8*i2;
            if (tok < 49) {
                qkv[tok*100 + cg]      = a0[i2];
                qkv[tok*100 + cg + 32] = a1[i2];
                qkv[tok*100 + cg + 64] = a2[i2];
            }
        }
    }
    __syncthreads();

    for (int e = t; e < 49*49; e += 256) {
        int i2 = e / 49, j = e % 49;
        float acc = 0.f;
        #pragma unroll
        for (int k = 0; k < 32; k += 4) {
            const float4 q4 = *reinterpret_cast<const float4*>(&qkv[i2*100 + k]);
            const float4 k4 = *reinterpret_cast<const float4*>(&qkv[j*100 + 32 + k]);
            acc = dot4(q4, k4, acc);
        }
        acc *= SCALE_ATTN;
        int xi = i2 / 7, yi = i2 % 7, xj = j / 7, yj = j % 7;
        acc += pos_l[(xj - xi + 6)*13 + (yj - yi + 6)];
        if (SHIFTED) {
            if (wh == 15 && ((xi >= 4) != (xj >= 4))) acc = -1e30f;
            if (ww == 15 && ((yi >= 4) != (yj >= 4))) acc = -1e30f;
        }
        ybuf[i2*52 + j] = acc;
    }
    __syncthreads();

    if (t < 49) {
        float m = -1e30f;
        for (int j = 0; j < 49; ++j) m = fmaxf(m, ybuf[t*52 + j]);
        float s = 0.f;
        for (int j = 0; j < 49; ++j) {
            float ev = __expf(ybuf[t*52 + j] - m);
            ybuf[t*52 + j] = ev; s += ev;
        }
        float inv = 1.f / s;
        for (int j = 0; j < 49; ++j) ybuf[t*52 + j] *= inv;
    }
    __syncthreads();

    for (int e = t; e < 49*32; e += 256) {
        int tok = e >> 5, d = e & 31;
        float acc = 0.f;
        for (int j = 0; j < 49; ++j)
            acc = fmaf(ybuf[tok*52 + j], qkv[j*100 + 64 + d], acc);
        int ti = tok / 7, tj = tok % 7;
        int gi = wh*7 + ti + SH; if (gi >= HW) gi -= HW;
        int gj = ww*7 + tj + SH; if (gj >= HW) gj -= HW;
        o_buf[((size_t)((b*HW + gi)*HW + gj))*96 + h*32 + d] = acc;
    }
}

// ----------------- out-proj + residual: xp += o @ W + b --------------------
__global__ __launch_bounds__(256) void proj_kernel(
    const float* __restrict__ o_buf, const float* __restrict__ w,
    const float* __restrict__ bias, float* __restrict__ xp)
{
    __shared__ float o_t[64*100];
    __shared__ float wT[96*100];
    __shared__ float bs[96];
    const int t = threadIdx.x;
    const size_t tok0 = (size_t)blockIdx.x * 64;

    for (int e = t; e < 64*24; e += 256) {
        int r = e / 24, p = e % 24;
        *reinterpret_cast<float4*>(&o_t[r*100 + p*4]) =
            *reinterpret_cast<const float4*>(o_buf + (tok0 + r)*96 + p*4);
    }
    for (int e = t; e < 96*96; e += 256) {
        int k = e / 96, n = e % 96;
        wT[n*100 + k] = w[k*96 + n];
    }
    if (t < 96) bs[t] = bias[t];
    __syncthreads();

    const int cg = t & 31, tg = t >> 5;
    float a0[8], a1[8], a2[8];
    #pragma unroll
    for (int i = 0; i < 8; ++i) { a0[i]=0.f; a1[i]=0.f; a2[i]=0.f; }
    for (int k = 0; k < 96; k += 4) {
        const float4 w0 = *reinterpret_cast<const float4*>(&wT[cg*100 + k]);
        const float4 w1 = *reinterpret_cast<const float4*>(&wT[(cg+32)*100 + k]);
        const float4 w2 = *reinterpret_cast<const float4*>(&wT[(cg+64)*100 + k]);
        #pragma unroll
        for (int i = 0; i < 8; ++i) {
            const float4 y4 = *reinterpret_cast<const float4*>(&o_t[(tg*8+i)*100 + k]);
            a0[i] = dot4(y4, w0, a0[i]);
            a1[i] = dot4(y4, w1, a1[i]);
            a2[i] = dot4(y4, w2, a2[i]);
        }
    }
    #pragma unroll
    for (int i = 0; i < 8; ++i) {
        size_t g = (tok0 + tg*8 + i)*96;
        xp[g + cg]      += a0[i] + bs[cg];
        xp[g + cg + 32] += a1[i] + bs[cg + 32];
        xp[g + cg + 64] += a2[i] + bs[cg + 64];
    }
}

// ------------- weight prep: transpose + bf16-convert FF weights ------------
// ff1_w [2][96][384] -> w1T [2][384][96] bf16 ; ff2_w [2][384][96] -> w2T [2][96][384] bf16
__global__ __launch_bounds__(256) void prep_weights_kernel(
    const float* __restrict__ ff1, const float* __restrict__ ff2,
    short* __restrict__ w1T, short* __restrict__ w2T)
{
    int i = blockIdx.x * 256 + threadIdx.x;
    if (i < 73728) {
        int l = i / 36864, r = i % 36864, n = r / 96, k = r % 96;
        w1T[i] = f2bf(ff1[(size_t)l*36864 + k*384 + n]);
    } else if (i < 147456) {
        int j = i - 73728;
        int l = j / 36864, r = j % 36864, n = r / 384, k = r % 384;
        w2T[j] = f2bf(ff2[(size_t)l*36864 + k*96 + n]);
    }
}

// ------------- fused LN2 + FF1 + GELU + FF2 + residual (bf16 MFMA) ---------
// 256 tokens/block, 4 waves, wave tile 64x96 (4x6 fragments of 16x16x32)
__global__ __launch_bounds__(256, 1) void ff_mfma_kernel(
    float* __restrict__ xp,
    const float* __restrict__ ln_g, const float* __restrict__ ln_b,
    const short* __restrict__ w1T,   // [384][96] bf16 (N,K)
    const float* __restrict__ b1,
    const short* __restrict__ w2T,   // [96][384] bf16 (N,K)
    const float* __restrict__ b2)
{
    __shared__ short y_s[256*104];   // LN'd activations, bf16
    __shared__ short h_s[256*104];   // hidden chunk, bf16
    __shared__ short w1_s[96*104];   // W1^T chunk
    __shared__ short w2_s[96*104];   // W2^T chunk

    const int t = threadIdx.x;
    const int lane = t & 63;
    const int w = t >> 6;
    const int l15 = lane & 15, lhi = lane >> 4;
    const size_t tok0 = (size_t)blockIdx.x * 256;

    // ---- phase 0: coalesced load + register LN -> y_s bf16 ----
    {
        const int part = t & 7;      // 8 threads per row, 12 elems each
        const int rloc = t >> 3;     // 0..31
        float g[12], bb[12];
        #pragma unroll
        for (int j = 0; j < 3; ++j) {
            float4 gv = *reinterpret_cast<const float4*>(ln_g + part*12 + j*4);
            float4 bv = *reinterpret_cast<const float4*>(ln_b + part*12 + j*4);
            g[j*4+0]=gv.x; g[j*4+1]=gv.y; g[j*4+2]=gv.z; g[j*4+3]=gv.w;
            bb[j*4+0]=bv.x; bb[j*4+1]=bv.y; bb[j*4+2]=bv.z; bb[j*4+3]=bv.w;
        }
        for (int it = 0; it < 8; ++it) {
            int row = it*32 + rloc;
            const float* src = xp + (tok0 + row)*96 + part*12;
            float v[12];
            float4 v0 = *reinterpret_cast<const float4*>(src);
            float4 v1 = *reinterpret_cast<const float4*>(src + 4);
            float4 v2 = *reinterpret_cast<const float4*>(src + 8);
            v[0]=v0.x; v[1]=v0.y; v[2]=v0.z; v[3]=v0.w;
            v[4]=v1.x; v[5]=v1.y; v[6]=v1.z; v[7]=v1.w;
            v[8]=v2.x; v[9]=v2.y; v[10]=v2.z; v[11]=v2.w;
            float s = 0.f, s2 = 0.f;
            #pragma unroll
            for (int j = 0; j < 12; ++j) { s += v[j]; s2 += v[j]*v[j]; }
            #pragma unroll
            for (int m = 1; m < 8; m <<= 1) {
                s  += __shfl_xor(s,  m);
                s2 += __shfl_xor(s2, m);
            }
            float mu = s * (1.f/96.f);
            float var = s2 * (1.f/96.f) - mu*mu;
            float rs = rsqrtf(var + 1e-5f);
            unsigned* yw = reinterpret_cast<unsigned*>(y_s) + row*52 + part*6;
            #pragma unroll
            for (int j = 0; j < 6; ++j) {
                float lo = (v[2*j]   - mu)*rs*g[2*j]   + bb[2*j];
                float hi = (v[2*j+1] - mu)*rs*g[2*j+1] + bb[2*j+1];
                unsigned u = (unsigned)(unsigned short)f2bf(lo) |
                             ((unsigned)(unsigned short)f2bf(hi) << 16);
                yw[j] = u;
            }
        }
    }

    f32x4 zero; zero[0]=0.f; zero[1]=0.f; zero[2]=0.f; zero[3]=0.f;
    f32x4 acc2[4][6];
    #pragma unroll
    for (int m = 0; m < 4; ++m)
        #pragma unroll
        for (int n = 0; n < 6; ++n) acc2[m][n] = zero;

    const int abase = (w*64 + l15)*104 + lhi*8;   // shared A-read base (y/h)
    const int bbase = l15*104 + lhi*8;            // shared B-read base (w1/w2)

    for (int c = 0; c < 4; ++c) {
        __syncthreads();   // prev chunk fully consumed h_s / w?_s
        // stage weight chunks (bf16, coalesced 16B)
        for (int e = t; e < 1152; e += 256) {
            int r = e / 12, seg = e % 12;
            *reinterpret_cast<uint4*>(&w1_s[r*104 + seg*8]) =
                *reinterpret_cast<const uint4*>(w1T + (c*96 + r)*96 + seg*8);
            *reinterpret_cast<uint4*>(&w2_s[r*104 + seg*8]) =
                *reinterpret_cast<const uint4*>(w2T + r*384 + c*96 + seg*8);
        }
        __syncthreads();

        // FF1: acc1 = y @ W1_chunk
        f32x4 acc1[4][6];
        #pragma unroll
        for (int m = 0; m < 4; ++m)
            #pragma unroll
            for (int n = 0; n < 6; ++n) acc1[m][n] = zero;
        #pragma unroll
        for (int ks = 0; ks < 3; ++ks) {
            bf16x8 a[4], b[6];
            #pragma unroll
            for (int m = 0; m < 4; ++m)
                a[m] = *reinterpret_cast<const bf16x8*>(&y_s[abase + m*16*104 + ks*32]);
            #pragma unroll
            for (int n = 0; n < 6; ++n)
                b[n] = *reinterpret_cast<const bf16x8*>(&w1_s[bbase + n*16*104 + ks*32]);
            #pragma unroll
            for (int m = 0; m < 4; ++m)
                #pragma unroll
                for (int n = 0; n < 6; ++n)
                    acc1[m][n] = __builtin_amdgcn_mfma_f32_16x16x32_bf16(
                        a[m], b[n], acc1[m][n], 0, 0, 0);
        }

        // bias + GELU -> h_s (bf16)
        #pragma unroll
        for (int n = 0; n < 6; ++n) {
            float bias = b1[c*96 + n*16 + l15];
            #pragma unroll
            for (int m = 0; m < 4; ++m) {
                #pragma unroll
                for (int r = 0; r < 4; ++r) {
                    float hv = gelu_fast(acc1[m][n][r] + bias);
                    int row = w*64 + m*16 + lhi*4 + r;
                    h_s[row*104 + n*16 + l15] = f2bf(hv);
                }
            }
        }
        // no barrier needed: each wave reads only its own h rows (in-wave LDS order)

        // FF2 partial: acc2 += h_chunk @ W2_chunk
        #pragma unroll
        for (int ks = 0; ks < 3; ++ks) {
            bf16x8 a[4], b[6];
            #pragma unroll
            for (int m = 0; m < 4; ++m)
                a[m] = *reinterpret_cast<const bf16x8*>(&h_s[abase + m*16*104 + ks*32]);
            #pragma unroll
            for (int n = 0; n < 6; ++n)
                b[n] = *reinterpret_cast<const bf16x8*>(&w2_s[bbase + n*16*104 + ks*32]);
            #pragma unroll
            for (int m = 0; m < 4; ++m)
                #pragma unroll
                for (int n = 0; n < 6; ++n)
                    acc2[m][n] = __builtin_amdgcn_mfma_f32_16x16x32_bf16(
                        a[m], b[n], acc2[m][n], 0, 0, 0);
        }
    }

    // epilogue: xp += acc2 + b2
    #pragma unroll
    for (int n = 0; n < 6; ++n) {
        float bias = b2[n*16 + l15];
        #pragma unroll
        for (int m = 0; m < 4; ++m) {
            #pragma unroll
            for (int r = 0; r < 4; ++r) {
                size_t row = tok0 + w*64 + m*16 + lhi*4 + r;
                float* p = xp + row*96 + n*16 + l15;
                *p += acc2[m][n][r] + bias;
            }
        }
    }
}

// ------------- (b,112,112,96) -> (b,96,112,112) fp32 -----------------------
__global__ __launch_bounds__(256) void out_kernel(
    const float* __restrict__ xp, float* __restrict__ out)
{
    __shared__ float tile[64*100];
    const int t = threadIdx.x;
    const int b = blockIdx.y;
    const int p0 = blockIdx.x * 64;
    for (int e = t; e < 64*24; e += 256) {
        int r = e / 24, p = e % 24;
        *reinterpret_cast<float4*>(&tile[r*100 + p*4]) =
            *reinterpret_cast<const float4*>(xp + ((size_t)b*NPIX + p0 + r)*96 + p*4);
    }
    __syncthreads();
    for (int e = t; e < 96*64; e += 256) {
        int ch = e >> 6, p = e & 63;
        out[((size_t)(b*96 + ch))*NPIX + p0 + p] = tile[p*100 + ch];
    }
}

extern "C" void kernel_launch(void* const* d_in, const int* in_sizes, int n_in,
                              void* d_out, int out_size, void* d_ws, size_t ws_size,
                              hipStream_t stream)
{
    (void)in_sizes; (void)n_in; (void)out_size; (void)ws_size;
    const float* x     = (const float*)d_in[0];
    const float* pm_w  = (const float*)d_in[1];
    const float* pm_b  = (const float*)d_in[2];
    const float* ln1_g = (const float*)d_in[3];
    const float* ln1_b = (const float*)d_in[4];
    const float* qkv_w = (const float*)d_in[5];
    const float* pos   = (const float*)d_in[6];
    const float* out_w = (const float*)d_in[7];
    const float* out_b = (const float*)d_in[8];
    const float* ln2_g = (const float*)d_in[9];
    const float* ln2_b = (const float*)d_in[10];
    const float* ff1_w = (const float*)d_in[11];
    const float* ff1_b = (const float*)d_in[12];
    const float* ff2_w = (const float*)d_in[13];
    const float* ff2_b = (const float*)d_in[14];

    float* xp    = (float*)d_ws;
    float* o_buf = xp + (size_t)NTOK_TOTAL * 96;
    short* w1T_b = (short*)(o_buf + (size_t)NTOK_TOTAL * 96);  // [2][384][96]
    short* w2T_b = w1T_b + 2*384*96;                           // [2][96][384]

    prep_weights_kernel<<<576, 256, 0, stream>>>(ff1_w, ff2_w, w1T_b, w2T_b);
    patch_merge_kernel<<<dim3(7, 112, 16), 256, 0, stream>>>(x, pm_w, pm_b, xp);

    for (int L = 0; L < 2; ++L) {
        const float* qw = qkv_w + (size_t)L*96*288;
        const float* pt = pos + L*169;
        if (L == 0)
            attn_kernel<false><<<dim3(256,3,16), 256, 0, stream>>>(
                xp, ln1_g + L*96, ln1_b + L*96, qw, pt, o_buf);
        else
            attn_kernel<true><<<dim3(256,3,16), 256, 0, stream>>>(
                xp, ln1_g + L*96, ln1_b + L*96, qw, pt, o_buf);
        proj_kernel<<<3136, 256, 0, stream>>>(
            o_buf, out_w + (size_t)L*96*96, out_b + L*96, xp);
        ff_mfma_kernel<<<784, 256, 0, stream>>>(
            xp, ln2_g + L*96, ln2_b + L*96,
            w1T_b + (size_t)L*384*96, ff1_b + L*384,
            w2T_b + (size_t)L*96*384, ff2_b + L*96);
    }
    out_kernel<<<dim3(196, 16), 256, 0, stream>>>(xp, (float*)d_out);
}

// Round 4
// 664.643 us; speedup vs baseline: 4.3426x; 2.3222x over previous
//
#include <hip/hip_runtime.h>
#include <hip/hip_bf16.h>

#define HW 112
#define NPIX (HW*HW)            // 12544
#define NTOK_TOTAL (16*NPIX)    // 200704
#define SCALE_ATTN 0.17677669529663689f

typedef short bf16x8 __attribute__((ext_vector_type(8)));
typedef float f32x4 __attribute__((ext_vector_type(4)));

__device__ __forceinline__ short f2bf(float f) {
    __hip_bfloat16 h = __float2bfloat16(f);
    return *reinterpret_cast<short*>(&h);
}

// fast erf-based GELU (Abramowitz-Stegun 7.1.26, |err| < 1.5e-7)
__device__ __forceinline__ float gelu_fast(float x) {
    float s = x * 0.70710678118654752f;
    float a = fabsf(s);
    float t = __builtin_amdgcn_rcpf(1.0f + 0.3275911f * a);
    float p = t*(0.254829592f + t*(-0.284496736f + t*(1.421413741f
              + t*(-1.453152027f + t*1.061405429f))));
    float e = __expf(-a * a);
    float erf_a = 1.0f - p * e;
    float erf_s = s < 0.f ? -erf_a : erf_a;
    return 0.5f * x * (1.0f + erf_s);
}

// ---------------- patch merging: x (16,3,448,448) -> xp (16,112,112,96) ----
__global__ __launch_bounds__(256) void patch_merge_kernel(
    const float* __restrict__ x, const float* __restrict__ pm_w,
    const float* __restrict__ pm_b, float* __restrict__ xp)
{
    __shared__ float w_lds[48*96];
    __shared__ float in_lds[16*52];
    __shared__ float b_lds[96];
    const int t = threadIdx.x;
    const int jt = blockIdx.x, i = blockIdx.y, b = blockIdx.z;
    const int j0 = jt * 16;

    for (int e = t; e < 48*96; e += 256) w_lds[e] = pm_w[e];
    if (t < 96) b_lds[t] = pm_b[t];
    for (int e = t; e < 768; e += 256) {
        int r = e >> 6, col = e & 63;
        int c = r >> 2, kh = r & 3;
        float v = x[(((size_t)(b*3 + c))*448 + (4*i + kh))*448 + 4*j0 + col];
        in_lds[(col >> 2)*52 + c*16 + kh*4 + (col & 3)] = v;
    }
    __syncthreads();
    for (int e = t; e < 16*96; e += 256) {
        int pos = e / 96, ch = e % 96;
        float acc = b_lds[ch];
        #pragma unroll
        for (int k = 0; k < 48; ++k)
            acc = fmaf(in_lds[pos*52 + k], w_lds[k*96 + ch], acc);
        xp[((size_t)((b*HW + i)*HW) + j0 + pos)*96 + ch] = acc;
    }
}

// ------------- weight prep: bf16 + (N,K)-transpose of all GEMM weights -----
// w1T [2][384][96], w2T [2][96][384], qkvT [2][288][96], outT [2][96][96]
__global__ __launch_bounds__(256) void prep_weights_kernel(
    const float* __restrict__ ff1, const float* __restrict__ ff2,
    const float* __restrict__ qkv_w, const float* __restrict__ out_w,
    short* __restrict__ w1T, short* __restrict__ w2T,
    short* __restrict__ qkvT, short* __restrict__ outT)
{
    int i = blockIdx.x * 256 + threadIdx.x;
    if (i < 73728) {
        int l = i / 36864, r = i % 36864, n = r / 96, k = r % 96;
        w1T[i] = f2bf(ff1[(size_t)l*36864 + k*384 + n]);
    } else if (i < 147456) {
        int j = i - 73728;
        int l = j / 36864, r = j % 36864, n = r / 384, k = r % 384;
        w2T[j] = f2bf(ff2[(size_t)l*36864 + k*96 + n]);
    } else if (i < 202752) {
        int j = i - 147456;
        int l = j / 27648, r = j % 27648, n = r / 96, k = r % 96;
        qkvT[j] = f2bf(qkv_w[(size_t)l*27648 + k*288 + n]);
    } else if (i < 221184) {
        int j = i - 202752;
        int l = j / 9216, r = j % 9216, n = r / 96, k = r % 96;
        outT[j] = f2bf(out_w[(size_t)l*9216 + k*96 + n]);
    }
}

// ---- fused LN1 + qkv + window attention + out-proj + residual (bf16 MFMA) --
// one block per (window, batch); 3 waves = 3 heads; 49 tokens padded to 64
template<bool SHIFTED>
__global__ __launch_bounds__(192) void attn_mfma_kernel(
    float* __restrict__ xp,
    const float* __restrict__ ln_g, const float* __restrict__ ln_b,
    const short* __restrict__ qkvT,   // [288][96] bf16 (N,K)
    const float* __restrict__ pos_tab,
    const short* __restrict__ outT,   // [96][96] bf16 (N,K)
    const float* __restrict__ out_b)
{
    __shared__ short bufA[13824];     // y_s[64][104] -> p_s[3][64][72] -> o_s[64][104]
    __shared__ short qk_s[13824];     // [h][tok][72]: q in cols 0..31, k in cols 32..63
    __shared__ short vT_s[6912];      // [h][d][72] = V^T (d rows, token cols)
    __shared__ float pos_l[169];
    __shared__ float ob_s[96];
    __shared__ float lng[96], lnb[96];

    const int t = threadIdx.x;
    const int lane = t & 63;
    const int h = t >> 6;             // wave index == head
    const int l15 = lane & 15, lhi = lane >> 4;
    const int wh = blockIdx.x >> 4, ww = blockIdx.x & 15;
    const int b = blockIdx.y;
    const int SH = SHIFTED ? 3 : 0;

    if (t < 169) pos_l[t] = pos_tab[t];
    if (t < 96) { lng[t] = ln_g[t]; lnb[t] = ln_b[t]; ob_s[t] = out_b[t]; }
    __syncthreads();

    // ---- phase 0: gather (shift folded) + register LN -> y bf16 in bufA ----
    {
        const int part = t & 3;       // 4 threads/row, 24 ch each
        for (int row = t >> 2; row < 49; row += 48) {
            int ti = (row*37) >> 8, tj = row - ti*7;
            int gi = wh*7 + ti + SH; if (gi >= HW) gi -= HW;
            int gj = ww*7 + tj + SH; if (gj >= HW) gj -= HW;
            const float* src = xp + ((size_t)((b*HW + gi)*HW + gj))*96 + part*24;
            float v[24];
            #pragma unroll
            for (int q4 = 0; q4 < 6; ++q4) {
                float4 vv = *reinterpret_cast<const float4*>(src + q4*4);
                v[q4*4+0]=vv.x; v[q4*4+1]=vv.y; v[q4*4+2]=vv.z; v[q4*4+3]=vv.w;
            }
            float s = 0.f, s2 = 0.f;
            #pragma unroll
            for (int j = 0; j < 24; ++j) { s += v[j]; s2 += v[j]*v[j]; }
            s  += __shfl_xor(s, 1);  s  += __shfl_xor(s, 2);
            s2 += __shfl_xor(s2, 1); s2 += __shfl_xor(s2, 2);
            float mu = s * (1.f/96.f);
            float var = s2 * (1.f/96.f) - mu*mu;
            float rs = rsqrtf(var + 1e-5f);
            unsigned* yw = reinterpret_cast<unsigned*>(bufA) + row*52 + part*12;
            #pragma unroll
            for (int j = 0; j < 12; ++j) {
                int c = part*24 + 2*j;
                float lo = (v[2*j]   - mu)*rs*lng[c]   + lnb[c];
                float hi = (v[2*j+1] - mu)*rs*lng[c+1] + lnb[c+1];
                yw[j] = (unsigned)(unsigned short)f2bf(lo) |
                        ((unsigned)(unsigned short)f2bf(hi) << 16);
            }
        }
        for (int e = t; e < 15*52; e += 192)
            reinterpret_cast<unsigned*>(bufA)[(49 + e/52)*52 + e%52] = 0u;
    }
    __syncthreads();

    // ---- phase 1: qkv for this wave's head (72 MFMA) ----
    {
        f32x4 acc[3][2][4];
        #pragma unroll
        for (int p = 0; p < 3; ++p)
            #pragma unroll
            for (int s = 0; s < 2; ++s)
                #pragma unroll
                for (int m = 0; m < 4; ++m)
                    { acc[p][s][m][0]=0.f; acc[p][s][m][1]=0.f; acc[p][s][m][2]=0.f; acc[p][s][m][3]=0.f; }
        #pragma unroll
        for (int ks = 0; ks < 3; ++ks) {
            bf16x8 a[4];
            #pragma unroll
            for (int m = 0; m < 4; ++m)
                a[m] = *reinterpret_cast<const bf16x8*>(&bufA[(m*16 + l15)*104 + ks*32 + lhi*8]);
            #pragma unroll
            for (int p = 0; p < 3; ++p)
                #pragma unroll
                for (int s = 0; s < 2; ++s) {
                    bf16x8 bf = *reinterpret_cast<const bf16x8*>(
                        qkvT + (p*96 + h*32 + s*16 + l15)*96 + ks*32 + lhi*8);
                    #pragma unroll
                    for (int m = 0; m < 4; ++m)
                        acc[p][s][m] = __builtin_amdgcn_mfma_f32_16x16x32_bf16(
                            a[m], bf, acc[p][s][m], 0, 0, 0);
                }
        }
        #pragma unroll
        for (int p = 0; p < 3; ++p)
            #pragma unroll
            for (int s = 0; s < 2; ++s)
                #pragma unroll
                for (int m = 0; m < 4; ++m)
                    #pragma unroll
                    for (int r = 0; r < 4; ++r) {
                        int tok = m*16 + lhi*4 + r;
                        int c = s*16 + l15;
                        short val = f2bf(acc[p][s][m][r]);
                        if (p == 0)      qk_s[h*4608 + tok*72 + c] = val;
                        else if (p == 1) qk_s[h*4608 + tok*72 + 32 + c] = val;
                        else             vT_s[h*2304 + c*72 + tok] = val;
                    }
    }
    __syncthreads();   // all y reads done (bufA will be re-used as P)

    // ---- phase 2: S = QK^T * scale + bias (+mask), softmax, P -> bufA ----
    float pv[4][4][4];   // [Mt][Nt][r]
    {
        f32x4 sacc[4][4];
        #pragma unroll
        for (int m = 0; m < 4; ++m)
            #pragma unroll
            for (int n = 0; n < 4; ++n)
                { sacc[m][n][0]=0.f; sacc[m][n][1]=0.f; sacc[m][n][2]=0.f; sacc[m][n][3]=0.f; }
        bf16x8 aq[4], bk[4];
        #pragma unroll
        for (int m = 0; m < 4; ++m)
            aq[m] = *reinterpret_cast<const bf16x8*>(&qk_s[h*4608 + (m*16 + l15)*72 + lhi*8]);
        #pragma unroll
        for (int n = 0; n < 4; ++n)
            bk[n] = *reinterpret_cast<const bf16x8*>(&qk_s[h*4608 + (n*16 + l15)*72 + 32 + lhi*8]);
        #pragma unroll
        for (int m = 0; m < 4; ++m)
            #pragma unroll
            for (int n = 0; n < 4; ++n)
                sacc[m][n] = __builtin_amdgcn_mfma_f32_16x16x32_bf16(aq[m], bk[n], sacc[m][n], 0, 0, 0);

        #pragma unroll
        for (int m = 0; m < 4; ++m)
            #pragma unroll
            for (int n = 0; n < 4; ++n)
                #pragma unroll
                for (int r = 0; r < 4; ++r) {
                    int i = m*16 + lhi*4 + r, j = n*16 + l15;
                    float v;
                    if (i >= 49 || j >= 49) v = -1e30f;
                    else {
                        int xi = (i*37) >> 8, yi = i - xi*7;
                        int xj = (j*37) >> 8, yj = j - xj*7;
                        v = sacc[m][n][r]*SCALE_ATTN + pos_l[(xj - xi + 6)*13 + (yj - yi + 6)];
                        if (SHIFTED) {
                            if (wh == 15 && ((xi >= 4) != (xj >= 4))) v = -1e30f;
                            if (ww == 15 && ((yi >= 4) != (yj >= 4))) v = -1e30f;
                        }
                    }
                    pv[m][n][r] = v;
                }
    }
    #pragma unroll
    for (int m = 0; m < 4; ++m)
        #pragma unroll
        for (int r = 0; r < 4; ++r) {
            float mx = fmaxf(fmaxf(pv[m][0][r], pv[m][1][r]), fmaxf(pv[m][2][r], pv[m][3][r]));
            mx = fmaxf(mx, __shfl_xor(mx, 1)); mx = fmaxf(mx, __shfl_xor(mx, 2));
            mx = fmaxf(mx, __shfl_xor(mx, 4)); mx = fmaxf(mx, __shfl_xor(mx, 8));
            float e0 = __expf(pv[m][0][r] - mx), e1 = __expf(pv[m][1][r] - mx);
            float e2 = __expf(pv[m][2][r] - mx), e3 = __expf(pv[m][3][r] - mx);
            float s = e0 + e1 + e2 + e3;
            s += __shfl_xor(s, 1); s += __shfl_xor(s, 2);
            s += __shfl_xor(s, 4); s += __shfl_xor(s, 8);
            float inv = 1.f / s;
            pv[m][0][r] = e0*inv; pv[m][1][r] = e1*inv;
            pv[m][2][r] = e2*inv; pv[m][3][r] = e3*inv;
        }
    #pragma unroll
    for (int m = 0; m < 4; ++m)
        #pragma unroll
        for (int n = 0; n < 4; ++n)
            #pragma unroll
            for (int r = 0; r < 4; ++r)
                bufA[h*4608 + (m*16 + lhi*4 + r)*72 + n*16 + l15] = f2bf(pv[m][n][r]);

    // ---- phase 3: O = P @ V (16 MFMA) ----
    f32x4 oacc[2][4];
    #pragma unroll
    for (int n = 0; n < 2; ++n)
        #pragma unroll
        for (int m = 0; m < 4; ++m)
            { oacc[n][m][0]=0.f; oacc[n][m][1]=0.f; oacc[n][m][2]=0.f; oacc[n][m][3]=0.f; }
    #pragma unroll
    for (int ks = 0; ks < 2; ++ks) {
        bf16x8 ap[4], bv[2];
        #pragma unroll
        for (int m = 0; m < 4; ++m)
            ap[m] = *reinterpret_cast<const bf16x8*>(&bufA[h*4608 + (m*16 + l15)*72 + ks*32 + lhi*8]);
        #pragma unroll
        for (int n = 0; n < 2; ++n)
            bv[n] = *reinterpret_cast<const bf16x8*>(&vT_s[h*2304 + (n*16 + l15)*72 + ks*32 + lhi*8]);
        #pragma unroll
        for (int n = 0; n < 2; ++n)
            #pragma unroll
            for (int m = 0; m < 4; ++m)
                oacc[n][m] = __builtin_amdgcn_mfma_f32_16x16x32_bf16(ap[m], bv[n], oacc[n][m], 0, 0, 0);
    }
    __syncthreads();   // all P reads done (bufA re-used as O)
    #pragma unroll
    for (int n = 0; n < 2; ++n)
        #pragma unroll
        for (int m = 0; m < 4; ++m)
            #pragma unroll
            for (int r = 0; r < 4; ++r)
                bufA[(m*16 + lhi*4 + r)*104 + h*32 + n*16 + l15] = f2bf(oacc[n][m][r]);
    __syncthreads();

    // ---- phase 4: out-proj (24 MFMA) + bias + residual scatter ----
    {
        f32x4 pacc[2][4];
        #pragma unroll
        for (int n = 0; n < 2; ++n)
            #pragma unroll
            for (int m = 0; m < 4; ++m)
                { pacc[n][m][0]=0.f; pacc[n][m][1]=0.f; pacc[n][m][2]=0.f; pacc[n][m][3]=0.f; }
        #pragma unroll
        for (int ks = 0; ks < 3; ++ks) {
            bf16x8 ao[4], bw[2];
            #pragma unroll
            for (int m = 0; m < 4; ++m)
                ao[m] = *reinterpret_cast<const bf16x8*>(&bufA[(m*16 + l15)*104 + ks*32 + lhi*8]);
            #pragma unroll
            for (int n = 0; n < 2; ++n)
                bw[n] = *reinterpret_cast<const bf16x8*>(
                    outT + ((h*2 + n)*16 + l15)*96 + ks*32 + lhi*8);
            #pragma unroll
            for (int n = 0; n < 2; ++n)
                #pragma unroll
                for (int m = 0; m < 4; ++m)
                    pacc[n][m] = __builtin_amdgcn_mfma_f32_16x16x32_bf16(ao[m], bw[n], pacc[n][m], 0, 0, 0);
        }
        #pragma unroll
        for (int m = 0; m < 4; ++m)
            #pragma unroll
            for (int r = 0; r < 4; ++r) {
                int tok = m*16 + lhi*4 + r;
                if (tok < 49) {
                    int ti = (tok*37) >> 8, tj = tok - ti*7;
                    int gi = wh*7 + ti + SH; if (gi >= HW) gi -= HW;
                    int gj = ww*7 + tj + SH; if (gj >= HW) gj -= HW;
                    float* dst = xp + ((size_t)((b*HW + gi)*HW + gj))*96;
                    #pragma unroll
                    for (int n = 0; n < 2; ++n) {
                        int ch = (h*2 + n)*16 + l15;
                        dst[ch] += pacc[n][m][r] + ob_s[ch];
                    }
                }
            }
    }
}

// ------------- fused LN2 + FF1 + GELU + FF2 + residual (bf16 MFMA) ---------
__global__ __launch_bounds__(256, 1) void ff_mfma_kernel(
    float* __restrict__ xp,
    const float* __restrict__ ln_g, const float* __restrict__ ln_b,
    const short* __restrict__ w1T,   // [384][96] bf16 (N,K)
    const float* __restrict__ b1,
    const short* __restrict__ w2T,   // [96][384] bf16 (N,K)
    const float* __restrict__ b2)
{
    __shared__ short y_s[256*104];
    __shared__ short h_s[256*104];
    __shared__ short w1_s[96*104];
    __shared__ short w2_s[96*104];

    const int t = threadIdx.x;
    const int lane = t & 63;
    const int w = t >> 6;
    const int l15 = lane & 15, lhi = lane >> 4;
    const size_t tok0 = (size_t)blockIdx.x * 256;

    {
        const int part = t & 7;
        const int rloc = t >> 3;
        float g[12], bb[12];
        #pragma unroll
        for (int j = 0; j < 3; ++j) {
            float4 gv = *reinterpret_cast<const float4*>(ln_g + part*12 + j*4);
            float4 bv = *reinterpret_cast<const float4*>(ln_b + part*12 + j*4);
            g[j*4+0]=gv.x; g[j*4+1]=gv.y; g[j*4+2]=gv.z; g[j*4+3]=gv.w;
            bb[j*4+0]=bv.x; bb[j*4+1]=bv.y; bb[j*4+2]=bv.z; bb[j*4+3]=bv.w;
        }
        for (int it = 0; it < 8; ++it) {
            int row = it*32 + rloc;
            const float* src = xp + (tok0 + row)*96 + part*12;
            float v[12];
            float4 v0 = *reinterpret_cast<const float4*>(src);
            float4 v1 = *reinterpret_cast<const float4*>(src + 4);
            float4 v2 = *reinterpret_cast<const float4*>(src + 8);
            v[0]=v0.x; v[1]=v0.y; v[2]=v0.z; v[3]=v0.w;
            v[4]=v1.x; v[5]=v1.y; v[6]=v1.z; v[7]=v1.w;
            v[8]=v2.x; v[9]=v2.y; v[10]=v2.z; v[11]=v2.w;
            float s = 0.f, s2 = 0.f;
            #pragma unroll
            for (int j = 0; j < 12; ++j) { s += v[j]; s2 += v[j]*v[j]; }
            #pragma unroll
            for (int m = 1; m < 8; m <<= 1) {
                s  += __shfl_xor(s,  m);
                s2 += __shfl_xor(s2, m);
            }
            float mu = s * (1.f/96.f);
            float var = s2 * (1.f/96.f) - mu*mu;
            float rs = rsqrtf(var + 1e-5f);
            unsigned* yw = reinterpret_cast<unsigned*>(y_s) + row*52 + part*6;
            #pragma unroll
            for (int j = 0; j < 6; ++j) {
                float lo = (v[2*j]   - mu)*rs*g[2*j]   + bb[2*j];
                float hi = (v[2*j+1] - mu)*rs*g[2*j+1] + bb[2*j+1];
                yw[j] = (unsigned)(unsigned short)f2bf(lo) |
                        ((unsigned)(unsigned short)f2bf(hi) << 16);
            }
        }
    }

    f32x4 zero; zero[0]=0.f; zero[1]=0.f; zero[2]=0.f; zero[3]=0.f;
    f32x4 acc2[4][6];
    #pragma unroll
    for (int m = 0; m < 4; ++m)
        #pragma unroll
        for (int n = 0; n < 6; ++n) acc2[m][n] = zero;

    const int abase = (w*64 + l15)*104 + lhi*8;
    const int bbase = l15*104 + lhi*8;

    for (int c = 0; c < 4; ++c) {
        __syncthreads();
        for (int e = t; e < 1152; e += 256) {
            int r = e / 12, seg = e % 12;
            *reinterpret_cast<uint4*>(&w1_s[r*104 + seg*8]) =
                *reinterpret_cast<const uint4*>(w1T + (c*96 + r)*96 + seg*8);
            *reinterpret_cast<uint4*>(&w2_s[r*104 + seg*8]) =
                *reinterpret_cast<const uint4*>(w2T + r*384 + c*96 + seg*8);
        }
        __syncthreads();

        f32x4 acc1[4][6];
        #pragma unroll
        for (int m = 0; m < 4; ++m)
            #pragma unroll
            for (int n = 0; n < 6; ++n) acc1[m][n] = zero;
        #pragma unroll
        for (int ks = 0; ks < 3; ++ks) {
            bf16x8 a[4], b[6];
            #pragma unroll
            for (int m = 0; m < 4; ++m)
                a[m] = *reinterpret_cast<const bf16x8*>(&y_s[abase + m*16*104 + ks*32]);
            #pragma unroll
            for (int n = 0; n < 6; ++n)
                b[n] = *reinterpret_cast<const bf16x8*>(&w1_s[bbase + n*16*104 + ks*32]);
            #pragma unroll
            for (int m = 0; m < 4; ++m)
                #pragma unroll
                for (int n = 0; n < 6; ++n)
                    acc1[m][n] = __builtin_amdgcn_mfma_f32_16x16x32_bf16(
                        a[m], b[n], acc1[m][n], 0, 0, 0);
        }

        #pragma unroll
        for (int n = 0; n < 6; ++n) {
            float bias = b1[c*96 + n*16 + l15];
            #pragma unroll
            for (int m = 0; m < 4; ++m) {
                #pragma unroll
                for (int r = 0; r < 4; ++r) {
                    float hv = gelu_fast(acc1[m][n][r] + bias);
                    int row = w*64 + m*16 + lhi*4 + r;
                    h_s[row*104 + n*16 + l15] = f2bf(hv);
                }
            }
        }

        #pragma unroll
        for (int ks = 0; ks < 3; ++ks) {
            bf16x8 a[4], b[6];
            #pragma unroll
            for (int m = 0; m < 4; ++m)
                a[m] = *reinterpret_cast<const bf16x8*>(&h_s[abase + m*16*104 + ks*32]);
            #pragma unroll
            for (int n = 0; n < 6; ++n)
                b[n] = *reinterpret_cast<const bf16x8*>(&w2_s[bbase + n*16*104 + ks*32]);
            #pragma unroll
            for (int m = 0; m < 4; ++m)
                #pragma unroll
                for (int n = 0; n < 6; ++n)
                    acc2[m][n] = __builtin_amdgcn_mfma_f32_16x16x32_bf16(
                        a[m], b[n], acc2[m][n], 0, 0, 0);
        }
    }

    #pragma unroll
    for (int n = 0; n < 6; ++n) {
        float bias = b2[n*16 + l15];
        #pragma unroll
        for (int m = 0; m < 4; ++m) {
            #pragma unroll
            for (int r = 0; r < 4; ++r) {
                size_t row = tok0 + w*64 + m*16 + lhi*4 + r;
                float* p = xp + row*96 + n*16 + l15;
                *p += acc2[m][n][r] + bias;
            }
        }
    }
}

// ------------- (b,112,112,96) -> (b,96,112,112) fp32 -----------------------
__global__ __launch_bounds__(256) void out_kernel(
    const float* __restrict__ xp, float* __restrict__ out)
{
    __shared__ float tile[64*100];
    const int t = threadIdx.x;
    const int b = blockIdx.y;
    const int p0 = blockIdx.x * 64;
    for (int e = t; e < 64*24; e += 256) {
        int r = e / 24, p = e % 24;
        *reinterpret_cast<float4*>(&tile[r*100 + p*4]) =
            *reinterpret_cast<const float4*>(xp + ((size_t)b*NPIX + p0 + r)*96 + p*4);
    }
    __syncthreads();
    for (int e = t; e < 96*64; e += 256) {
        int ch = e >> 6, p = e & 63;
        out[((size_t)(b*96 + ch))*NPIX + p0 + p] = tile[p*100 + ch];
    }
}

extern "C" void kernel_launch(void* const* d_in, const int* in_sizes, int n_in,
                              void* d_out, int out_size, void* d_ws, size_t ws_size,
                              hipStream_t stream)
{
    (void)in_sizes; (void)n_in; (void)out_size; (void)ws_size;
    const float* x     = (const float*)d_in[0];
    const float* pm_w  = (const float*)d_in[1];
    const float* pm_b  = (const float*)d_in[2];
    const float* ln1_g = (const float*)d_in[3];
    const float* ln1_b = (const float*)d_in[4];
    const float* qkv_w = (const float*)d_in[5];
    const float* pos   = (const float*)d_in[6];
    const float* out_w = (const float*)d_in[7];
    const float* out_b = (const float*)d_in[8];
    const float* ln2_g = (const float*)d_in[9];
    const float* ln2_b = (const float*)d_in[10];
    const float* ff1_w = (const float*)d_in[11];
    const float* ff1_b = (const float*)d_in[12];
    const float* ff2_w = (const float*)d_in[13];
    const float* ff2_b = (const float*)d_in[14];

    float* xp    = (float*)d_ws;
    short* w1T_b = (short*)(xp + (size_t)NTOK_TOTAL * 96);  // [2][384][96]
    short* w2T_b = w1T_b + 2*384*96;                        // [2][96][384]
    short* qkvT_b = w2T_b + 2*96*384;                       // [2][288][96]
    short* outT_b = qkvT_b + 2*288*96;                      // [2][96][96]

    prep_weights_kernel<<<864, 256, 0, stream>>>(ff1_w, ff2_w, qkv_w, out_w,
                                                 w1T_b, w2T_b, qkvT_b, outT_b);
    patch_merge_kernel<<<dim3(7, 112, 16), 256, 0, stream>>>(x, pm_w, pm_b, xp);

    for (int L = 0; L < 2; ++L) {
        if (L == 0)
            attn_mfma_kernel<false><<<dim3(256, 16), 192, 0, stream>>>(
                xp, ln1_g, ln1_b, qkvT_b, pos, outT_b, out_b);
        else
            attn_mfma_kernel<true><<<dim3(256, 16), 192, 0, stream>>>(
                xp, ln1_g + 96, ln1_b + 96, qkvT_b + 27648, pos + 169,
                outT_b + 9216, out_b + 96);
        ff_mfma_kernel<<<784, 256, 0, stream>>>(
            xp, ln2_g + L*96, ln2_b + L*96,
            w1T_b + (size_t)L*384*96, ff1_b + L*384,
            w2T_b + (size_t)L*96*384, ff2_b + L*96);
    }
    out_kernel<<<dim3(196, 16), 256, 0, stream>>>(xp, (float*)d_out);
}

// Round 5
// 611.817 us; speedup vs baseline: 4.7176x; 1.0863x over previous
//
#include <hip/hip_runtime.h>
#include <hip/hip_bf16.h>

#define HW 112
#define NPIX (HW*HW)            // 12544
#define NTOK_TOTAL (16*NPIX)    // 200704
#define SCALE_ATTN 0.17677669529663689f

typedef short bf16x8 __attribute__((ext_vector_type(8)));
typedef float f32x4 __attribute__((ext_vector_type(4)));

__device__ __forceinline__ short f2bf(float f) {
    __hip_bfloat16 h = __float2bfloat16(f);
    return *reinterpret_cast<short*>(&h);
}

// fast erf-based GELU (Abramowitz-Stegun 7.1.26, |err| < 1.5e-7)
__device__ __forceinline__ float gelu_fast(float x) {
    float s = x * 0.70710678118654752f;
    float a = fabsf(s);
    float t = __builtin_amdgcn_rcpf(1.0f + 0.3275911f * a);
    float p = t*(0.254829592f + t*(-0.284496736f + t*(1.421413741f
              + t*(-1.453152027f + t*1.061405429f))));
    float e = __expf(-a * a);
    float erf_a = 1.0f - p * e;
    float erf_s = s < 0.f ? -erf_a : erf_a;
    return 0.5f * x * (1.0f + erf_s);
}

// tanh-form GELU: x * sigmoid(1.5957691*x + 0.0713548*x^3); |err| ~3e-4
// written inf-safe as x*(1 - 1/(e+1))
__device__ __forceinline__ float gelu_tanh(float x) {
    float t  = x * x;
    float m1 = fmaf(0.071354816f, t, 1.5957691f);
    float e  = __expf(x * m1);
    float r  = __builtin_amdgcn_rcpf(e + 1.0f);
    return fmaf(-x, r, x);
}

// ---------------- patch merging: x (16,3,448,448) -> xp (16,112,112,96) ----
__global__ __launch_bounds__(256) void patch_merge_kernel(
    const float* __restrict__ x, const float* __restrict__ pm_w,
    const float* __restrict__ pm_b, float* __restrict__ xp)
{
    __shared__ float w_lds[48*96];
    __shared__ float in_lds[16*52];
    __shared__ float b_lds[96];
    const int t = threadIdx.x;
    const int jt = blockIdx.x, i = blockIdx.y, b = blockIdx.z;
    const int j0 = jt * 16;

    for (int e = t; e < 48*96; e += 256) w_lds[e] = pm_w[e];
    if (t < 96) b_lds[t] = pm_b[t];
    for (int e = t; e < 768; e += 256) {
        int r = e >> 6, col = e & 63;
        int c = r >> 2, kh = r & 3;
        float v = x[(((size_t)(b*3 + c))*448 + (4*i + kh))*448 + 4*j0 + col];
        in_lds[(col >> 2)*52 + c*16 + kh*4 + (col & 3)] = v;
    }
    __syncthreads();
    for (int e = t; e < 16*96; e += 256) {
        int pos = e / 96, ch = e % 96;
        float acc = b_lds[ch];
        #pragma unroll
        for (int k = 0; k < 48; ++k)
            acc = fmaf(in_lds[pos*52 + k], w_lds[k*96 + ch], acc);
        xp[((size_t)((b*HW + i)*HW) + j0 + pos)*96 + ch] = acc;
    }
}

// ------------- weight prep: bf16 + (N,K)-transpose of all GEMM weights -----
// w1T [2][384][96], w2T [2][96][384], qkvT [2][288][96], outT [2][96][96]
__global__ __launch_bounds__(256) void prep_weights_kernel(
    const float* __restrict__ ff1, const float* __restrict__ ff2,
    const float* __restrict__ qkv_w, const float* __restrict__ out_w,
    short* __restrict__ w1T, short* __restrict__ w2T,
    short* __restrict__ qkvT, short* __restrict__ outT)
{
    int i = blockIdx.x * 256 + threadIdx.x;
    if (i < 73728) {
        int l = i / 36864, r = i % 36864, n = r / 96, k = r % 96;
        w1T[i] = f2bf(ff1[(size_t)l*36864 + k*384 + n]);
    } else if (i < 147456) {
        int j = i - 73728;
        int l = j / 36864, r = j % 36864, n = r / 384, k = r % 384;
        w2T[j] = f2bf(ff2[(size_t)l*36864 + k*96 + n]);
    } else if (i < 202752) {
        int j = i - 147456;
        int l = j / 27648, r = j % 27648, n = r / 96, k = r % 96;
        qkvT[j] = f2bf(qkv_w[(size_t)l*27648 + k*288 + n]);
    } else if (i < 221184) {
        int j = i - 202752;
        int l = j / 9216, r = j % 9216, n = r / 96, k = r % 96;
        outT[j] = f2bf(out_w[(size_t)l*9216 + k*96 + n]);
    }
}

// ---- fused LN1 + qkv + window attention + out-proj + residual (bf16 MFMA) --
// one block per (window, batch); 3 waves = 3 heads; 49 tokens padded to 64
template<bool SHIFTED>
__global__ __launch_bounds__(192) void attn_mfma_kernel(
    float* __restrict__ xp,
    const float* __restrict__ ln_g, const float* __restrict__ ln_b,
    const short* __restrict__ qkvT,   // [288][96] bf16 (N,K)
    const float* __restrict__ pos_tab,
    const short* __restrict__ outT,   // [96][96] bf16 (N,K)
    const float* __restrict__ out_b)
{
    __shared__ short bufA[13824];     // y_s[64][104] -> p_s[3][64][72] -> o_s[64][104]
    __shared__ short qk_s[13824];     // [h][tok][72]: q in cols 0..31, k in cols 32..63
    __shared__ short vT_s[6912];      // [h][d][72] = V^T (d rows, token cols)
    __shared__ float pos_l[169];
    __shared__ float ob_s[96];
    __shared__ float lng[96], lnb[96];

    const int t = threadIdx.x;
    const int lane = t & 63;
    const int h = t >> 6;             // wave index == head
    const int l15 = lane & 15, lhi = lane >> 4;
    const int wh = blockIdx.x >> 4, ww = blockIdx.x & 15;
    const int b = blockIdx.y;
    const int SH = SHIFTED ? 3 : 0;

    if (t < 169) pos_l[t] = pos_tab[t];
    if (t < 96) { lng[t] = ln_g[t]; lnb[t] = ln_b[t]; ob_s[t] = out_b[t]; }
    __syncthreads();

    // ---- phase 0: gather (shift folded) + register LN -> y bf16 in bufA ----
    {
        const int part = t & 3;       // 4 threads/row, 24 ch each
        for (int row = t >> 2; row < 49; row += 48) {
            int ti = (row*37) >> 8, tj = row - ti*7;
            int gi = wh*7 + ti + SH; if (gi >= HW) gi -= HW;
            int gj = ww*7 + tj + SH; if (gj >= HW) gj -= HW;
            const float* src = xp + ((size_t)((b*HW + gi)*HW + gj))*96 + part*24;
            float v[24];
            #pragma unroll
            for (int q4 = 0; q4 < 6; ++q4) {
                float4 vv = *reinterpret_cast<const float4*>(src + q4*4);
                v[q4*4+0]=vv.x; v[q4*4+1]=vv.y; v[q4*4+2]=vv.z; v[q4*4+3]=vv.w;
            }
            float s = 0.f, s2 = 0.f;
            #pragma unroll
            for (int j = 0; j < 24; ++j) { s += v[j]; s2 += v[j]*v[j]; }
            s  += __shfl_xor(s, 1);  s  += __shfl_xor(s, 2);
            s2 += __shfl_xor(s2, 1); s2 += __shfl_xor(s2, 2);
            float mu = s * (1.f/96.f);
            float var = s2 * (1.f/96.f) - mu*mu;
            float rs = rsqrtf(var + 1e-5f);
            unsigned* yw = reinterpret_cast<unsigned*>(bufA) + row*52 + part*12;
            #pragma unroll
            for (int j = 0; j < 12; ++j) {
                int c = part*24 + 2*j;
                float lo = (v[2*j]   - mu)*rs*lng[c]   + lnb[c];
                float hi = (v[2*j+1] - mu)*rs*lng[c+1] + lnb[c+1];
                yw[j] = (unsigned)(unsigned short)f2bf(lo) |
                        ((unsigned)(unsigned short)f2bf(hi) << 16);
            }
        }
        for (int e = t; e < 15*52; e += 192)
            reinterpret_cast<unsigned*>(bufA)[(49 + e/52)*52 + e%52] = 0u;
    }
    __syncthreads();

    // ---- phase 1: qkv for this wave's head (72 MFMA) ----
    {
        f32x4 acc[3][2][4];
        #pragma unroll
        for (int p = 0; p < 3; ++p)
            #pragma unroll
            for (int s = 0; s < 2; ++s)
                #pragma unroll
                for (int m = 0; m < 4; ++m)
                    { acc[p][s][m][0]=0.f; acc[p][s][m][1]=0.f; acc[p][s][m][2]=0.f; acc[p][s][m][3]=0.f; }
        #pragma unroll
        for (int ks = 0; ks < 3; ++ks) {
            bf16x8 a[4];
            #pragma unroll
            for (int m = 0; m < 4; ++m)
                a[m] = *reinterpret_cast<const bf16x8*>(&bufA[(m*16 + l15)*104 + ks*32 + lhi*8]);
            #pragma unroll
            for (int p = 0; p < 3; ++p)
                #pragma unroll
                for (int s = 0; s < 2; ++s) {
                    bf16x8 bf = *reinterpret_cast<const bf16x8*>(
                        qkvT + (p*96 + h*32 + s*16 + l15)*96 + ks*32 + lhi*8);
                    #pragma unroll
                    for (int m = 0; m < 4; ++m)
                        acc[p][s][m] = __builtin_amdgcn_mfma_f32_16x16x32_bf16(
                            a[m], bf, acc[p][s][m], 0, 0, 0);
                }
        }
        #pragma unroll
        for (int p = 0; p < 3; ++p)
            #pragma unroll
            for (int s = 0; s < 2; ++s)
                #pragma unroll
                for (int m = 0; m < 4; ++m)
                    #pragma unroll
                    for (int r = 0; r < 4; ++r) {
                        int tok = m*16 + lhi*4 + r;
                        int c = s*16 + l15;
                        short val = f2bf(acc[p][s][m][r]);
                        if (p == 0)      qk_s[h*4608 + tok*72 + c] = val;
                        else if (p == 1) qk_s[h*4608 + tok*72 + 32 + c] = val;
                        else             vT_s[h*2304 + c*72 + tok] = val;
                    }
    }
    __syncthreads();   // all y reads done (bufA will be re-used as P)

    // ---- phase 2: S = QK^T * scale + bias (+mask), softmax, P -> bufA ----
    float pv[4][4][4];   // [Mt][Nt][r]
    {
        f32x4 sacc[4][4];
        #pragma unroll
        for (int m = 0; m < 4; ++m)
            #pragma unroll
            for (int n = 0; n < 4; ++n)
                { sacc[m][n][0]=0.f; sacc[m][n][1]=0.f; sacc[m][n][2]=0.f; sacc[m][n][3]=0.f; }
        bf16x8 aq[4], bk[4];
        #pragma unroll
        for (int m = 0; m < 4; ++m)
            aq[m] = *reinterpret_cast<const bf16x8*>(&qk_s[h*4608 + (m*16 + l15)*72 + lhi*8]);
        #pragma unroll
        for (int n = 0; n < 4; ++n)
            bk[n] = *reinterpret_cast<const bf16x8*>(&qk_s[h*4608 + (n*16 + l15)*72 + 32 + lhi*8]);
        #pragma unroll
        for (int m = 0; m < 4; ++m)
            #pragma unroll
            for (int n = 0; n < 4; ++n)
                sacc[m][n] = __builtin_amdgcn_mfma_f32_16x16x32_bf16(aq[m], bk[n], sacc[m][n], 0, 0, 0);

        #pragma unroll
        for (int m = 0; m < 4; ++m)
            #pragma unroll
            for (int n = 0; n < 4; ++n)
                #pragma unroll
                for (int r = 0; r < 4; ++r) {
                    int i = m*16 + lhi*4 + r, j = n*16 + l15;
                    float v;
                    if (i >= 49 || j >= 49) v = -1e30f;
                    else {
                        int xi = (i*37) >> 8, yi = i - xi*7;
                        int xj = (j*37) >> 8, yj = j - xj*7;
                        v = sacc[m][n][r]*SCALE_ATTN + pos_l[(xj - xi + 6)*13 + (yj - yi + 6)];
                        if (SHIFTED) {
                            if (wh == 15 && ((xi >= 4) != (xj >= 4))) v = -1e30f;
                            if (ww == 15 && ((yi >= 4) != (yj >= 4))) v = -1e30f;
                        }
                    }
                    pv[m][n][r] = v;
                }
    }
    #pragma unroll
    for (int m = 0; m < 4; ++m)
        #pragma unroll
        for (int r = 0; r < 4; ++r) {
            float mx = fmaxf(fmaxf(pv[m][0][r], pv[m][1][r]), fmaxf(pv[m][2][r], pv[m][3][r]));
            mx = fmaxf(mx, __shfl_xor(mx, 1)); mx = fmaxf(mx, __shfl_xor(mx, 2));
            mx = fmaxf(mx, __shfl_xor(mx, 4)); mx = fmaxf(mx, __shfl_xor(mx, 8));
            float e0 = __expf(pv[m][0][r] - mx), e1 = __expf(pv[m][1][r] - mx);
            float e2 = __expf(pv[m][2][r] - mx), e3 = __expf(pv[m][3][r] - mx);
            float s = e0 + e1 + e2 + e3;
            s += __shfl_xor(s, 1); s += __shfl_xor(s, 2);
            s += __shfl_xor(s, 4); s += __shfl_xor(s, 8);
            float inv = 1.f / s;
            pv[m][0][r] = e0*inv; pv[m][1][r] = e1*inv;
            pv[m][2][r] = e2*inv; pv[m][3][r] = e3*inv;
        }
    #pragma unroll
    for (int m = 0; m < 4; ++m)
        #pragma unroll
        for (int n = 0; n < 4; ++n)
            #pragma unroll
            for (int r = 0; r < 4; ++r)
                bufA[h*4608 + (m*16 + lhi*4 + r)*72 + n*16 + l15] = f2bf(pv[m][n][r]);

    // ---- phase 3: O = P @ V (16 MFMA) ----
    f32x4 oacc[2][4];
    #pragma unroll
    for (int n = 0; n < 2; ++n)
        #pragma unroll
        for (int m = 0; m < 4; ++m)
            { oacc[n][m][0]=0.f; oacc[n][m][1]=0.f; oacc[n][m][2]=0.f; oacc[n][m][3]=0.f; }
    #pragma unroll
    for (int ks = 0; ks < 2; ++ks) {
        bf16x8 ap[4], bv[2];
        #pragma unroll
        for (int m = 0; m < 4; ++m)
            ap[m] = *reinterpret_cast<const bf16x8*>(&bufA[h*4608 + (m*16 + l15)*72 + ks*32 + lhi*8]);
        #pragma unroll
        for (int n = 0; n < 2; ++n)
            bv[n] = *reinterpret_cast<const bf16x8*>(&vT_s[h*2304 + (n*16 + l15)*72 + ks*32 + lhi*8]);
        #pragma unroll
        for (int n = 0; n < 2; ++n)
            #pragma unroll
            for (int m = 0; m < 4; ++m)
                oacc[n][m] = __builtin_amdgcn_mfma_f32_16x16x32_bf16(ap[m], bv[n], oacc[n][m], 0, 0, 0);
    }
    __syncthreads();   // all P reads done (bufA re-used as O)
    #pragma unroll
    for (int n = 0; n < 2; ++n)
        #pragma unroll
        for (int m = 0; m < 4; ++m)
            #pragma unroll
            for (int r = 0; r < 4; ++r)
                bufA[(m*16 + lhi*4 + r)*104 + h*32 + n*16 + l15] = f2bf(oacc[n][m][r]);
    __syncthreads();

    // ---- phase 4: out-proj (24 MFMA) + bias + residual scatter ----
    {
        f32x4 pacc[2][4];
        #pragma unroll
        for (int n = 0; n < 2; ++n)
            #pragma unroll
            for (int m = 0; m < 4; ++m)
                { pacc[n][m][0]=0.f; pacc[n][m][1]=0.f; pacc[n][m][2]=0.f; pacc[n][m][3]=0.f; }
        #pragma unroll
        for (int ks = 0; ks < 3; ++ks) {
            bf16x8 ao[4], bw[2];
            #pragma unroll
            for (int m = 0; m < 4; ++m)
                ao[m] = *reinterpret_cast<const bf16x8*>(&bufA[(m*16 + l15)*104 + ks*32 + lhi*8]);
            #pragma unroll
            for (int n = 0; n < 2; ++n)
                bw[n] = *reinterpret_cast<const bf16x8*>(
                    outT + ((h*2 + n)*16 + l15)*96 + ks*32 + lhi*8);
            #pragma unroll
            for (int n = 0; n < 2; ++n)
                #pragma unroll
                for (int m = 0; m < 4; ++m)
                    pacc[n][m] = __builtin_amdgcn_mfma_f32_16x16x32_bf16(ao[m], bw[n], pacc[n][m], 0, 0, 0);
        }
        #pragma unroll
        for (int m = 0; m < 4; ++m)
            #pragma unroll
            for (int r = 0; r < 4; ++r) {
                int tok = m*16 + lhi*4 + r;
                if (tok < 49) {
                    int ti = (tok*37) >> 8, tj = tok - ti*7;
                    int gi = wh*7 + ti + SH; if (gi >= HW) gi -= HW;
                    int gj = ww*7 + tj + SH; if (gj >= HW) gj -= HW;
                    float* dst = xp + ((size_t)((b*HW + gi)*HW + gj))*96;
                    #pragma unroll
                    for (int n = 0; n < 2; ++n) {
                        int ch = (h*2 + n)*16 + l15;
                        dst[ch] += pacc[n][m][r] + ob_s[ch];
                    }
                }
            }
    }
}

// ------------- fused LN2 + FF1 + GELU + FF2 + residual (bf16 MFMA) ---------
// 64 tokens/block, 2 waves, wave tile 32x96; weights read direct from L2
__global__ __launch_bounds__(128) void ff_mfma_kernel(
    float* __restrict__ xp,
    const float* __restrict__ ln_g, const float* __restrict__ ln_b,
    const short* __restrict__ w1T,   // [384][96] bf16 (N,K)
    const float* __restrict__ b1,
    const short* __restrict__ w2T,   // [96][384] bf16 (N,K)
    const float* __restrict__ b2)
{
    __shared__ short y_s[64*104];    // LN'd activations, bf16
    __shared__ short h_s[64*104];    // hidden chunk, bf16

    const int t = threadIdx.x;
    const int lane = t & 63;
    const int w = t >> 6;            // 0..1
    const int l15 = lane & 15, lhi = lane >> 4;
    const size_t tok0 = (size_t)blockIdx.x * 64;

    // ---- phase 0: coalesced load + register LN -> y_s bf16 ----
    {
        const int part = t & 3;      // 4 threads/row, 24 ch each
        const int rbase = t >> 2;    // 0..31
        float g[24], bb[24];
        #pragma unroll
        for (int q4 = 0; q4 < 6; ++q4) {
            float4 gv = *reinterpret_cast<const float4*>(ln_g + part*24 + q4*4);
            float4 bv = *reinterpret_cast<const float4*>(ln_b + part*24 + q4*4);
            g[q4*4+0]=gv.x; g[q4*4+1]=gv.y; g[q4*4+2]=gv.z; g[q4*4+3]=gv.w;
            bb[q4*4+0]=bv.x; bb[q4*4+1]=bv.y; bb[q4*4+2]=bv.z; bb[q4*4+3]=bv.w;
        }
        #pragma unroll
        for (int it = 0; it < 2; ++it) {
            int row = it*32 + rbase;
            const float* src = xp + (tok0 + row)*96 + part*24;
            float v[24];
            #pragma unroll
            for (int q4 = 0; q4 < 6; ++q4) {
                float4 vv = *reinterpret_cast<const float4*>(src + q4*4);
                v[q4*4+0]=vv.x; v[q4*4+1]=vv.y; v[q4*4+2]=vv.z; v[q4*4+3]=vv.w;
            }
            float s = 0.f, s2 = 0.f;
            #pragma unroll
            for (int j = 0; j < 24; ++j) { s += v[j]; s2 += v[j]*v[j]; }
            s  += __shfl_xor(s, 1);  s  += __shfl_xor(s, 2);
            s2 += __shfl_xor(s2, 1); s2 += __shfl_xor(s2, 2);
            float mu = s * (1.f/96.f);
            float var = s2 * (1.f/96.f) - mu*mu;
            float rs = rsqrtf(var + 1e-5f);
            unsigned* yw = reinterpret_cast<unsigned*>(y_s) + row*52 + part*12;
            #pragma unroll
            for (int j = 0; j < 12; ++j) {
                float lo = (v[2*j]   - mu)*rs*g[2*j]   + bb[2*j];
                float hi = (v[2*j+1] - mu)*rs*g[2*j+1] + bb[2*j+1];
                yw[j] = (unsigned)(unsigned short)f2bf(lo) |
                        ((unsigned)(unsigned short)f2bf(hi) << 16);
            }
        }
    }
    __syncthreads();   // the only block-wide barrier

    f32x4 zero; zero[0]=0.f; zero[1]=0.f; zero[2]=0.f; zero[3]=0.f;
    f32x4 acc2[2][6];
    #pragma unroll
    for (int m = 0; m < 2; ++m)
        #pragma unroll
        for (int n = 0; n < 6; ++n) acc2[m][n] = zero;

    const int abase = (w*32 + l15)*104 + lhi*8;   // A-read base (y/h), own rows

    #pragma unroll
    for (int c = 0; c < 4; ++c) {
        // FF1: acc1 = y @ W1_chunk (B-frags direct from global/L2)
        f32x4 acc1[2][6];
        #pragma unroll
        for (int m = 0; m < 2; ++m)
            #pragma unroll
            for (int n = 0; n < 6; ++n) acc1[m][n] = zero;
        #pragma unroll
        for (int ks = 0; ks < 3; ++ks) {
            bf16x8 a[2];
            #pragma unroll
            for (int m = 0; m < 2; ++m)
                a[m] = *reinterpret_cast<const bf16x8*>(&y_s[abase + m*16*104 + ks*32]);
            #pragma unroll
            for (int n = 0; n < 6; ++n) {
                bf16x8 bw = *reinterpret_cast<const bf16x8*>(
                    w1T + (c*96 + n*16 + l15)*96 + ks*32 + lhi*8);
                #pragma unroll
                for (int m = 0; m < 2; ++m)
                    acc1[m][n] = __builtin_amdgcn_mfma_f32_16x16x32_bf16(
                        a[m], bw, acc1[m][n], 0, 0, 0);
            }
        }

        // bias + GELU -> h_s (bf16); own rows only, no barrier needed
        #pragma unroll
        for (int n = 0; n < 6; ++n) {
            float bias = b1[c*96 + n*16 + l15];
            #pragma unroll
            for (int m = 0; m < 2; ++m) {
                #pragma unroll
                for (int r = 0; r < 4; ++r) {
                    float hv = gelu_tanh(acc1[m][n][r] + bias);
                    int row = w*32 + m*16 + lhi*4 + r;
                    h_s[row*104 + n*16 + l15] = f2bf(hv);
                }
            }
        }

        // FF2 partial: acc2 += h_chunk @ W2_chunk
        #pragma unroll
        for (int ks = 0; ks < 3; ++ks) {
            bf16x8 a[2];
            #pragma unroll
            for (int m = 0; m < 2; ++m)
                a[m] = *reinterpret_cast<const bf16x8*>(&h_s[abase + m*16*104 + ks*32]);
            #pragma unroll
            for (int n = 0; n < 6; ++n) {
                bf16x8 bw = *reinterpret_cast<const bf16x8*>(
                    w2T + (n*16 + l15)*384 + c*96 + ks*32 + lhi*8);
                #pragma unroll
                for (int m = 0; m < 2; ++m)
                    acc2[m][n] = __builtin_amdgcn_mfma_f32_16x16x32_bf16(
                        a[m], bw, acc2[m][n], 0, 0, 0);
            }
        }
    }

    // epilogue: xp += acc2 + b2
    #pragma unroll
    for (int n = 0; n < 6; ++n) {
        float bias = b2[n*16 + l15];
        #pragma unroll
        for (int m = 0; m < 2; ++m) {
            #pragma unroll
            for (int r = 0; r < 4; ++r) {
                size_t row = tok0 + w*32 + m*16 + lhi*4 + r;
                float* p = xp + row*96 + n*16 + l15;
                *p += acc2[m][n][r] + bias;
            }
        }
    }
}

// ------------- (b,112,112,96) -> (b,96,112,112) fp32 -----------------------
__global__ __launch_bounds__(256) void out_kernel(
    const float* __restrict__ xp, float* __restrict__ out)
{
    __shared__ float tile[64*100];
    const int t = threadIdx.x;
    const int b = blockIdx.y;
    const int p0 = blockIdx.x * 64;
    for (int e = t; e < 64*24; e += 256) {
        int r = e / 24, p = e % 24;
        *reinterpret_cast<float4*>(&tile[r*100 + p*4]) =
            *reinterpret_cast<const float4*>(xp + ((size_t)b*NPIX + p0 + r)*96 + p*4);
    }
    __syncthreads();
    for (int e = t; e < 96*64; e += 256) {
        int ch = e >> 6, p = e & 63;
        out[((size_t)(b*96 + ch))*NPIX + p0 + p] = tile[p*100 + ch];
    }
}

extern "C" void kernel_launch(void* const* d_in, const int* in_sizes, int n_in,
                              void* d_out, int out_size, void* d_ws, size_t ws_size,
                              hipStream_t stream)
{
    (void)in_sizes; (void)n_in; (void)out_size; (void)ws_size;
    const float* x     = (const float*)d_in[0];
    const float* pm_w  = (const float*)d_in[1];
    const float* pm_b  = (const float*)d_in[2];
    const float* ln1_g = (const float*)d_in[3];
    const float* ln1_b = (const float*)d_in[4];
    const float* qkv_w = (const float*)d_in[5];
    const float* pos   = (const float*)d_in[6];
    const float* out_w = (const float*)d_in[7];
    const float* out_b = (const float*)d_in[8];
    const float* ln2_g = (const float*)d_in[9];
    const float* ln2_b = (const float*)d_in[10];
    const float* ff1_w = (const float*)d_in[11];
    const float* ff1_b = (const float*)d_in[12];
    const float* ff2_w = (const float*)d_in[13];
    const float* ff2_b = (const float*)d_in[14];

    float* xp    = (float*)d_ws;
    short* w1T_b = (short*)(xp + (size_t)NTOK_TOTAL * 96);  // [2][384][96]
    short* w2T_b = w1T_b + 2*384*96;                        // [2][96][384]
    short* qkvT_b = w2T_b + 2*96*384;                       // [2][288][96]
    short* outT_b = qkvT_b + 2*288*96;                      // [2][96][96]

    prep_weights_kernel<<<864, 256, 0, stream>>>(ff1_w, ff2_w, qkv_w, out_w,
                                                 w1T_b, w2T_b, qkvT_b, outT_b);
    patch_merge_kernel<<<dim3(7, 112, 16), 256, 0, stream>>>(x, pm_w, pm_b, xp);

    for (int L = 0; L < 2; ++L) {
        if (L == 0)
            attn_mfma_kernel<false><<<dim3(256, 16), 192, 0, stream>>>(
                xp, ln1_g, ln1_b, qkvT_b, pos, outT_b, out_b);
        else
            attn_mfma_kernel<true><<<dim3(256, 16), 192, 0, stream>>>(
                xp, ln1_g + 96, ln1_b + 96, qkvT_b + 27648, pos + 169,
                outT_b + 9216, out_b + 96);
        ff_mfma_kernel<<<3136, 128, 0, stream>>>(
            xp, ln2_g + L*96, ln2_b + L*96,
            w1T_b + (size_t)L*384*96, ff1_b + L*384,
            w2T_b + (size_t)L*96*384, ff2_b + L*96);
    }
    out_kernel<<<dim3(196, 16), 256, 0, stream>>>(xp, (float*)d_out);
}

// Round 6
// 603.186 us; speedup vs baseline: 4.7851x; 1.0143x over previous
//
#include <hip/hip_runtime.h>
#include <hip/hip_bf16.h>

#define HW 112
#define NPIX (HW*HW)            // 12544
#define NTOK_TOTAL (16*NPIX)    // 200704
#define SCALE_ATTN 0.17677669529663689f

typedef short bf16x8 __attribute__((ext_vector_type(8)));
typedef float f32x4 __attribute__((ext_vector_type(4)));

__device__ __forceinline__ short f2bf(float f) {
    __hip_bfloat16 h = __float2bfloat16(f);
    return *reinterpret_cast<short*>(&h);
}

// tanh-form GELU: x * sigmoid(1.5957691*x + 0.0713548*x^3); |err| ~3e-4
// written inf-safe as x*(1 - 1/(e+1))
__device__ __forceinline__ float gelu_tanh(float x) {
    float t  = x * x;
    float m1 = fmaf(0.071354816f, t, 1.5957691f);
    float e  = __expf(x * m1);
    float r  = __builtin_amdgcn_rcpf(e + 1.0f);
    return fmaf(-x, r, x);
}

// ---------------- patch merging: x (16,3,448,448) -> xp (16,112,112,96) ----
__global__ __launch_bounds__(256) void patch_merge_kernel(
    const float* __restrict__ x, const float* __restrict__ pm_w,
    const float* __restrict__ pm_b, float* __restrict__ xp)
{
    __shared__ float w_lds[48*96];
    __shared__ float in_lds[16*52];
    __shared__ float b_lds[96];
    const int t = threadIdx.x;
    const int jt = blockIdx.x, i = blockIdx.y, b = blockIdx.z;
    const int j0 = jt * 16;

    for (int e = t; e < 48*96; e += 256) w_lds[e] = pm_w[e];
    if (t < 96) b_lds[t] = pm_b[t];
    for (int e = t; e < 768; e += 256) {
        int r = e >> 6, col = e & 63;
        int c = r >> 2, kh = r & 3;
        float v = x[(((size_t)(b*3 + c))*448 + (4*i + kh))*448 + 4*j0 + col];
        in_lds[(col >> 2)*52 + c*16 + kh*4 + (col & 3)] = v;
    }
    __syncthreads();
    for (int e = t; e < 16*96; e += 256) {
        int pos = e / 96, ch = e % 96;
        float acc = b_lds[ch];
        #pragma unroll
        for (int k = 0; k < 48; ++k)
            acc = fmaf(in_lds[pos*52 + k], w_lds[k*96 + ch], acc);
        xp[((size_t)((b*HW + i)*HW) + j0 + pos)*96 + ch] = acc;
    }
}

// ------------- weight prep: bf16 + (N,K)-transpose of all GEMM weights -----
// w1T [2][384][96], w2T [2][96][384], qkvT [2][288][96], outT [2][96][96]
__global__ __launch_bounds__(256) void prep_weights_kernel(
    const float* __restrict__ ff1, const float* __restrict__ ff2,
    const float* __restrict__ qkv_w, const float* __restrict__ out_w,
    short* __restrict__ w1T, short* __restrict__ w2T,
    short* __restrict__ qkvT, short* __restrict__ outT)
{
    int i = blockIdx.x * 256 + threadIdx.x;
    if (i < 73728) {
        int l = i / 36864, r = i % 36864, n = r / 96, k = r % 96;
        w1T[i] = f2bf(ff1[(size_t)l*36864 + k*384 + n]);
    } else if (i < 147456) {
        int j = i - 73728;
        int l = j / 36864, r = j % 36864, n = r / 384, k = r % 384;
        w2T[j] = f2bf(ff2[(size_t)l*36864 + k*96 + n]);
    } else if (i < 202752) {
        int j = i - 147456;
        int l = j / 27648, r = j % 27648, n = r / 96, k = r % 96;
        qkvT[j] = f2bf(qkv_w[(size_t)l*27648 + k*288 + n]);
    } else if (i < 221184) {
        int j = i - 202752;
        int l = j / 9216, r = j % 9216, n = r / 96, k = r % 96;
        outT[j] = f2bf(out_w[(size_t)l*9216 + k*96 + n]);
    }
}

// ---- fused LN1 + qkv + window attention + out-proj + residual (bf16 MFMA) --
// one block per (window, batch); 3 waves = 3 heads; 49 tokens padded to 64
template<bool SHIFTED>
__global__ __launch_bounds__(192) void attn_mfma_kernel(
    float* __restrict__ xp,
    const float* __restrict__ ln_g, const float* __restrict__ ln_b,
    const short* __restrict__ qkvT,   // [288][96] bf16 (N,K)
    const float* __restrict__ pos_tab,
    const short* __restrict__ outT,   // [96][96] bf16 (N,K)
    const float* __restrict__ out_b)
{
    __shared__ short bufA[13824];     // y_s[64][104] -> p_s[3][64][72] -> o_s[64][104]
    __shared__ short qk_s[13824];     // [h][tok][72]: q in cols 0..31, k in cols 32..63
    __shared__ short vT_s[6912];      // [h][d][72] = V^T (d rows, token cols)
    __shared__ float pos_l[169];
    __shared__ float ob_s[96];
    __shared__ float lng[96], lnb[96];

    const int t = threadIdx.x;
    const int lane = t & 63;
    const int h = t >> 6;             // wave index == head
    const int l15 = lane & 15, lhi = lane >> 4;
    const int wh = blockIdx.x >> 4, ww = blockIdx.x & 15;
    const int b = blockIdx.y;
    const int SH = SHIFTED ? 3 : 0;

    if (t < 169) pos_l[t] = pos_tab[t];
    if (t < 96) { lng[t] = ln_g[t]; lnb[t] = ln_b[t]; ob_s[t] = out_b[t]; }
    __syncthreads();

    // ---- phase 0: gather (shift folded) + register LN -> y bf16 in bufA ----
    {
        const int part = t & 3;       // 4 threads/row, 24 ch each
        for (int row = t >> 2; row < 49; row += 48) {
            int ti = (row*37) >> 8, tj = row - ti*7;
            int gi = wh*7 + ti + SH; if (gi >= HW) gi -= HW;
            int gj = ww*7 + tj + SH; if (gj >= HW) gj -= HW;
            const float* src = xp + ((size_t)((b*HW + gi)*HW + gj))*96 + part*24;
            float v[24];
            #pragma unroll
            for (int q4 = 0; q4 < 6; ++q4) {
                float4 vv = *reinterpret_cast<const float4*>(src + q4*4);
                v[q4*4+0]=vv.x; v[q4*4+1]=vv.y; v[q4*4+2]=vv.z; v[q4*4+3]=vv.w;
            }
            float s = 0.f, s2 = 0.f;
            #pragma unroll
            for (int j = 0; j < 24; ++j) { s += v[j]; s2 += v[j]*v[j]; }
            s  += __shfl_xor(s, 1);  s  += __shfl_xor(s, 2);
            s2 += __shfl_xor(s2, 1); s2 += __shfl_xor(s2, 2);
            float mu = s * (1.f/96.f);
            float var = s2 * (1.f/96.f) - mu*mu;
            float rs = rsqrtf(var + 1e-5f);
            unsigned* yw = reinterpret_cast<unsigned*>(bufA) + row*52 + part*12;
            #pragma unroll
            for (int j = 0; j < 12; ++j) {
                int c = part*24 + 2*j;
                float lo = (v[2*j]   - mu)*rs*lng[c]   + lnb[c];
                float hi = (v[2*j+1] - mu)*rs*lng[c+1] + lnb[c+1];
                yw[j] = (unsigned)(unsigned short)f2bf(lo) |
                        ((unsigned)(unsigned short)f2bf(hi) << 16);
            }
        }
        for (int e = t; e < 15*52; e += 192)
            reinterpret_cast<unsigned*>(bufA)[(49 + e/52)*52 + e%52] = 0u;
    }
    __syncthreads();

    // ---- phase 1: qkv for this wave's head (72 MFMA) ----
    {
        f32x4 acc[3][2][4];
        #pragma unroll
        for (int p = 0; p < 3; ++p)
            #pragma unroll
            for (int s = 0; s < 2; ++s)
                #pragma unroll
                for (int m = 0; m < 4; ++m)
                    { acc[p][s][m][0]=0.f; acc[p][s][m][1]=0.f; acc[p][s][m][2]=0.f; acc[p][s][m][3]=0.f; }
        #pragma unroll
        for (int ks = 0; ks < 3; ++ks) {
            bf16x8 a[4];
            #pragma unroll
            for (int m = 0; m < 4; ++m)
                a[m] = *reinterpret_cast<const bf16x8*>(&bufA[(m*16 + l15)*104 + ks*32 + lhi*8]);
            #pragma unroll
            for (int p = 0; p < 3; ++p)
                #pragma unroll
                for (int s = 0; s < 2; ++s) {
                    bf16x8 bf = *reinterpret_cast<const bf16x8*>(
                        qkvT + (p*96 + h*32 + s*16 + l15)*96 + ks*32 + lhi*8);
                    #pragma unroll
                    for (int m = 0; m < 4; ++m)
                        acc[p][s][m] = __builtin_amdgcn_mfma_f32_16x16x32_bf16(
                            a[m], bf, acc[p][s][m], 0, 0, 0);
                }
        }
        #pragma unroll
        for (int p = 0; p < 3; ++p)
            #pragma unroll
            for (int s = 0; s < 2; ++s)
                #pragma unroll
                for (int m = 0; m < 4; ++m)
                    #pragma unroll
                    for (int r = 0; r < 4; ++r) {
                        int tok = m*16 + lhi*4 + r;
                        int c = s*16 + l15;
                        short val = f2bf(acc[p][s][m][r]);
                        if (p == 0)      qk_s[h*4608 + tok*72 + c] = val;
                        else if (p == 1) qk_s[h*4608 + tok*72 + 32 + c] = val;
                        else             vT_s[h*2304 + c*72 + tok] = val;
                    }
    }
    __syncthreads();   // all y reads done (bufA will be re-used as P)

    // ---- phase 2: S = QK^T * scale + bias (+mask), softmax, P -> bufA ----
    float pv[4][4][4];   // [Mt][Nt][r]
    {
        f32x4 sacc[4][4];
        #pragma unroll
        for (int m = 0; m < 4; ++m)
            #pragma unroll
            for (int n = 0; n < 4; ++n)
                { sacc[m][n][0]=0.f; sacc[m][n][1]=0.f; sacc[m][n][2]=0.f; sacc[m][n][3]=0.f; }
        bf16x8 aq[4], bk[4];
        #pragma unroll
        for (int m = 0; m < 4; ++m)
            aq[m] = *reinterpret_cast<const bf16x8*>(&qk_s[h*4608 + (m*16 + l15)*72 + lhi*8]);
        #pragma unroll
        for (int n = 0; n < 4; ++n)
            bk[n] = *reinterpret_cast<const bf16x8*>(&qk_s[h*4608 + (n*16 + l15)*72 + 32 + lhi*8]);
        #pragma unroll
        for (int m = 0; m < 4; ++m)
            #pragma unroll
            for (int n = 0; n < 4; ++n)
                sacc[m][n] = __builtin_amdgcn_mfma_f32_16x16x32_bf16(aq[m], bk[n], sacc[m][n], 0, 0, 0);

        #pragma unroll
        for (int m = 0; m < 4; ++m)
            #pragma unroll
            for (int n = 0; n < 4; ++n)
                #pragma unroll
                for (int r = 0; r < 4; ++r) {
                    int i = m*16 + lhi*4 + r, j = n*16 + l15;
                    float v;
                    if (i >= 49 || j >= 49) v = -1e30f;
                    else {
                        int xi = (i*37) >> 8, yi = i - xi*7;
                        int xj = (j*37) >> 8, yj = j - xj*7;
                        v = sacc[m][n][r]*SCALE_ATTN + pos_l[(xj - xi + 6)*13 + (yj - yi + 6)];
                        if (SHIFTED) {
                            if (wh == 15 && ((xi >= 4) != (xj >= 4))) v = -1e30f;
                            if (ww == 15 && ((yi >= 4) != (yj >= 4))) v = -1e30f;
                        }
                    }
                    pv[m][n][r] = v;
                }
    }
    #pragma unroll
    for (int m = 0; m < 4; ++m)
        #pragma unroll
        for (int r = 0; r < 4; ++r) {
            float mx = fmaxf(fmaxf(pv[m][0][r], pv[m][1][r]), fmaxf(pv[m][2][r], pv[m][3][r]));
            mx = fmaxf(mx, __shfl_xor(mx, 1)); mx = fmaxf(mx, __shfl_xor(mx, 2));
            mx = fmaxf(mx, __shfl_xor(mx, 4)); mx = fmaxf(mx, __shfl_xor(mx, 8));
            float e0 = __expf(pv[m][0][r] - mx), e1 = __expf(pv[m][1][r] - mx);
            float e2 = __expf(pv[m][2][r] - mx), e3 = __expf(pv[m][3][r] - mx);
            float s = e0 + e1 + e2 + e3;
            s += __shfl_xor(s, 1); s += __shfl_xor(s, 2);
            s += __shfl_xor(s, 4); s += __shfl_xor(s, 8);
            float inv = 1.f / s;
            pv[m][0][r] = e0*inv; pv[m][1][r] = e1*inv;
            pv[m][2][r] = e2*inv; pv[m][3][r] = e3*inv;
        }
    #pragma unroll
    for (int m = 0; m < 4; ++m)
        #pragma unroll
        for (int n = 0; n < 4; ++n)
            #pragma unroll
            for (int r = 0; r < 4; ++r)
                bufA[h*4608 + (m*16 + lhi*4 + r)*72 + n*16 + l15] = f2bf(pv[m][n][r]);

    // ---- phase 3: O = P @ V (16 MFMA) ----
    f32x4 oacc[2][4];
    #pragma unroll
    for (int n = 0; n < 2; ++n)
        #pragma unroll
        for (int m = 0; m < 4; ++m)
            { oacc[n][m][0]=0.f; oacc[n][m][1]=0.f; oacc[n][m][2]=0.f; oacc[n][m][3]=0.f; }
    #pragma unroll
    for (int ks = 0; ks < 2; ++ks) {
        bf16x8 ap[4], bv[2];
        #pragma unroll
        for (int m = 0; m < 4; ++m)
            ap[m] = *reinterpret_cast<const bf16x8*>(&bufA[h*4608 + (m*16 + l15)*72 + ks*32 + lhi*8]);
        #pragma unroll
        for (int n = 0; n < 2; ++n)
            bv[n] = *reinterpret_cast<const bf16x8*>(&vT_s[h*2304 + (n*16 + l15)*72 + ks*32 + lhi*8]);
        #pragma unroll
        for (int n = 0; n < 2; ++n)
            #pragma unroll
            for (int m = 0; m < 4; ++m)
                oacc[n][m] = __builtin_amdgcn_mfma_f32_16x16x32_bf16(ap[m], bv[n], oacc[n][m], 0, 0, 0);
    }
    __syncthreads();   // all P reads done (bufA re-used as O)
    #pragma unroll
    for (int n = 0; n < 2; ++n)
        #pragma unroll
        for (int m = 0; m < 4; ++m)
            #pragma unroll
            for (int r = 0; r < 4; ++r)
                bufA[(m*16 + lhi*4 + r)*104 + h*32 + n*16 + l15] = f2bf(oacc[n][m][r]);
    __syncthreads();

    // ---- phase 4: out-proj (24 MFMA) + bias + residual scatter ----
    {
        f32x4 pacc[2][4];
        #pragma unroll
        for (int n = 0; n < 2; ++n)
            #pragma unroll
            for (int m = 0; m < 4; ++m)
                { pacc[n][m][0]=0.f; pacc[n][m][1]=0.f; pacc[n][m][2]=0.f; pacc[n][m][3]=0.f; }
        #pragma unroll
        for (int ks = 0; ks < 3; ++ks) {
            bf16x8 ao[4], bw[2];
            #pragma unroll
            for (int m = 0; m < 4; ++m)
                ao[m] = *reinterpret_cast<const bf16x8*>(&bufA[(m*16 + l15)*104 + ks*32 + lhi*8]);
            #pragma unroll
            for (int n = 0; n < 2; ++n)
                bw[n] = *reinterpret_cast<const bf16x8*>(
                    outT + ((h*2 + n)*16 + l15)*96 + ks*32 + lhi*8);
            #pragma unroll
            for (int n = 0; n < 2; ++n)
                #pragma unroll
                for (int m = 0; m < 4; ++m)
                    pacc[n][m] = __builtin_amdgcn_mfma_f32_16x16x32_bf16(ao[m], bw[n], pacc[n][m], 0, 0, 0);
        }
        #pragma unroll
        for (int m = 0; m < 4; ++m)
            #pragma unroll
            for (int r = 0; r < 4; ++r) {
                int tok = m*16 + lhi*4 + r;
                if (tok < 49) {
                    int ti = (tok*37) >> 8, tj = tok - ti*7;
                    int gi = wh*7 + ti + SH; if (gi >= HW) gi -= HW;
                    int gj = ww*7 + tj + SH; if (gj >= HW) gj -= HW;
                    float* dst = xp + ((size_t)((b*HW + gi)*HW + gj))*96;
                    #pragma unroll
                    for (int n = 0; n < 2; ++n) {
                        int ch = (h*2 + n)*16 + l15;
                        dst[ch] += pacc[n][m][r] + ob_s[ch];
                    }
                }
            }
    }
}

// ------------- fused LN2 + FF1 + GELU + FF2 + residual (bf16 MFMA) ---------
// 32 tokens/block, ONE wave, tile 32x96; weights direct from L2; 12 blocks/CU
__global__ __launch_bounds__(64, 4) void ff_mfma_kernel(
    float* __restrict__ xp,
    const float* __restrict__ ln_g, const float* __restrict__ ln_b,
    const short* __restrict__ w1T,   // [384][96] bf16 (N,K)
    const float* __restrict__ b1,
    const short* __restrict__ w2T,   // [96][384] bf16 (N,K)
    const float* __restrict__ b2)
{
    __shared__ short y_s[32*104];    // LN'd activations, bf16
    __shared__ short h_s[32*104];    // hidden chunk, bf16

    const int t = threadIdx.x;       // 0..63
    const int l15 = t & 15, lhi = (t & 63) >> 4;
    const size_t tok0 = (size_t)blockIdx.x * 32;

    // ---- phase 0: coalesced load + register LN -> y_s bf16 ----
    {
        const int part = t & 3;      // 4 threads/row, 24 ch each
        const int rbase = t >> 2;    // 0..15
        float g[24], bb[24];
        #pragma unroll
        for (int q4 = 0; q4 < 6; ++q4) {
            float4 gv = *reinterpret_cast<const float4*>(ln_g + part*24 + q4*4);
            float4 bv = *reinterpret_cast<const float4*>(ln_b + part*24 + q4*4);
            g[q4*4+0]=gv.x; g[q4*4+1]=gv.y; g[q4*4+2]=gv.z; g[q4*4+3]=gv.w;
            bb[q4*4+0]=bv.x; bb[q4*4+1]=bv.y; bb[q4*4+2]=bv.z; bb[q4*4+3]=bv.w;
        }
        #pragma unroll
        for (int it = 0; it < 2; ++it) {
            int row = it*16 + rbase;
            const float* src = xp + (tok0 + row)*96 + part*24;
            float v[24];
            #pragma unroll
            for (int q4 = 0; q4 < 6; ++q4) {
                float4 vv = *reinterpret_cast<const float4*>(src + q4*4);
                v[q4*4+0]=vv.x; v[q4*4+1]=vv.y; v[q4*4+2]=vv.z; v[q4*4+3]=vv.w;
            }
            float s = 0.f, s2 = 0.f;
            #pragma unroll
            for (int j = 0; j < 24; ++j) { s += v[j]; s2 += v[j]*v[j]; }
            s  += __shfl_xor(s, 1);  s  += __shfl_xor(s, 2);
            s2 += __shfl_xor(s2, 1); s2 += __shfl_xor(s2, 2);
            float mu = s * (1.f/96.f);
            float var = s2 * (1.f/96.f) - mu*mu;
            float rs = rsqrtf(var + 1e-5f);
            unsigned* yw = reinterpret_cast<unsigned*>(y_s) + row*52 + part*12;
            #pragma unroll
            for (int j = 0; j < 12; ++j) {
                float lo = (v[2*j]   - mu)*rs*g[2*j]   + bb[2*j];
                float hi = (v[2*j+1] - mu)*rs*g[2*j+1] + bb[2*j+1];
                yw[j] = (unsigned)(unsigned short)f2bf(lo) |
                        ((unsigned)(unsigned short)f2bf(hi) << 16);
            }
        }
    }
    __syncthreads();   // single wave: cheap

    f32x4 zero; zero[0]=0.f; zero[1]=0.f; zero[2]=0.f; zero[3]=0.f;
    f32x4 acc2[2][6];
    #pragma unroll
    for (int m = 0; m < 2; ++m)
        #pragma unroll
        for (int n = 0; n < 6; ++n) acc2[m][n] = zero;

    const int abase = l15*104 + lhi*8;   // A-read base (y/h)

    #pragma unroll
    for (int c = 0; c < 4; ++c) {
        // FF1: acc1 = y @ W1_chunk (B-frags direct from global/L2)
        f32x4 acc1[2][6];
        #pragma unroll
        for (int m = 0; m < 2; ++m)
            #pragma unroll
            for (int n = 0; n < 6; ++n) acc1[m][n] = zero;
        #pragma unroll
        for (int ks = 0; ks < 3; ++ks) {
            bf16x8 a[2];
            #pragma unroll
            for (int m = 0; m < 2; ++m)
                a[m] = *reinterpret_cast<const bf16x8*>(&y_s[abase + m*16*104 + ks*32]);
            #pragma unroll
            for (int n = 0; n < 6; ++n) {
                bf16x8 bw = *reinterpret_cast<const bf16x8*>(
                    w1T + (c*96 + n*16 + l15)*96 + ks*32 + lhi*8);
                #pragma unroll
                for (int m = 0; m < 2; ++m)
                    acc1[m][n] = __builtin_amdgcn_mfma_f32_16x16x32_bf16(
                        a[m], bw, acc1[m][n], 0, 0, 0);
            }
        }

        // bias + GELU -> h_s (bf16); same wave, no barrier needed
        #pragma unroll
        for (int n = 0; n < 6; ++n) {
            float bias = b1[c*96 + n*16 + l15];
            #pragma unroll
            for (int m = 0; m < 2; ++m) {
                #pragma unroll
                for (int r = 0; r < 4; ++r) {
                    float hv = gelu_tanh(acc1[m][n][r] + bias);
                    int row = m*16 + lhi*4 + r;
                    h_s[row*104 + n*16 + l15] = f2bf(hv);
                }
            }
        }

        // FF2 partial: acc2 += h_chunk @ W2_chunk
        #pragma unroll
        for (int ks = 0; ks < 3; ++ks) {
            bf16x8 a[2];
            #pragma unroll
            for (int m = 0; m < 2; ++m)
                a[m] = *reinterpret_cast<const bf16x8*>(&h_s[abase + m*16*104 + ks*32]);
            #pragma unroll
            for (int n = 0; n < 6; ++n) {
                bf16x8 bw = *reinterpret_cast<const bf16x8*>(
                    w2T + (n*16 + l15)*384 + c*96 + ks*32 + lhi*8);
                #pragma unroll
                for (int m = 0; m < 2; ++m)
                    acc2[m][n] = __builtin_amdgcn_mfma_f32_16x16x32_bf16(
                        a[m], bw, acc2[m][n], 0, 0, 0);
            }
        }
    }

    // epilogue: xp += acc2 + b2
    #pragma unroll
    for (int n = 0; n < 6; ++n) {
        float bias = b2[n*16 + l15];
        #pragma unroll
        for (int m = 0; m < 2; ++m) {
            #pragma unroll
            for (int r = 0; r < 4; ++r) {
                size_t row = tok0 + m*16 + lhi*4 + r;
                float* p = xp + row*96 + n*16 + l15;
                *p += acc2[m][n][r] + bias;
            }
        }
    }
}

// ------------- (b,112,112,96) -> (b,96,112,112) fp32 -----------------------
__global__ __launch_bounds__(256) void out_kernel(
    const float* __restrict__ xp, float* __restrict__ out)
{
    __shared__ float tile[64*100];
    const int t = threadIdx.x;
    const int b = blockIdx.y;
    const int p0 = blockIdx.x * 64;
    for (int e = t; e < 64*24; e += 256) {
        int r = e / 24, p = e % 24;
        *reinterpret_cast<float4*>(&tile[r*100 + p*4]) =
            *reinterpret_cast<const float4*>(xp + ((size_t)b*NPIX + p0 + r)*96 + p*4);
    }
    __syncthreads();
    for (int e = t; e < 96*64; e += 256) {
        int ch = e >> 6, p = e & 63;
        out[((size_t)(b*96 + ch))*NPIX + p0 + p] = tile[p*100 + ch];
    }
}

extern "C" void kernel_launch(void* const* d_in, const int* in_sizes, int n_in,
                              void* d_out, int out_size, void* d_ws, size_t ws_size,
                              hipStream_t stream)
{
    (void)in_sizes; (void)n_in; (void)out_size; (void)ws_size;
    const float* x     = (const float*)d_in[0];
    const float* pm_w  = (const float*)d_in[1];
    const float* pm_b  = (const float*)d_in[2];
    const float* ln1_g = (const float*)d_in[3];
    const float* ln1_b = (const float*)d_in[4];
    const float* qkv_w = (const float*)d_in[5];
    const float* pos   = (const float*)d_in[6];
    const float* out_w = (const float*)d_in[7];
    const float* out_b = (const float*)d_in[8];
    const float* ln2_g = (const float*)d_in[9];
    const float* ln2_b = (const float*)d_in[10];
    const float* ff1_w = (const float*)d_in[11];
    const float* ff1_b = (const float*)d_in[12];
    const float* ff2_w = (const float*)d_in[13];
    const float* ff2_b = (const float*)d_in[14];

    float* xp    = (float*)d_ws;
    short* w1T_b = (short*)(xp + (size_t)NTOK_TOTAL * 96);  // [2][384][96]
    short* w2T_b = w1T_b + 2*384*96;                        // [2][96][384]
    short* qkvT_b = w2T_b + 2*96*384;                       // [2][288][96]
    short* outT_b = qkvT_b + 2*288*96;                      // [2][96][96]

    prep_weights_kernel<<<864, 256, 0, stream>>>(ff1_w, ff2_w, qkv_w, out_w,
                                                 w1T_b, w2T_b, qkvT_b, outT_b);
    patch_merge_kernel<<<dim3(7, 112, 16), 256, 0, stream>>>(x, pm_w, pm_b, xp);

    for (int L = 0; L < 2; ++L) {
        if (L == 0)
            attn_mfma_kernel<false><<<dim3(256, 16), 192, 0, stream>>>(
                xp, ln1_g, ln1_b, qkvT_b, pos, outT_b, out_b);
        else
            attn_mfma_kernel<true><<<dim3(256, 16), 192, 0, stream>>>(
                xp, ln1_g + 96, ln1_b + 96, qkvT_b + 27648, pos + 169,
                outT_b + 9216, out_b + 96);
        ff_mfma_kernel<<<6272, 64, 0, stream>>>(
            xp, ln2_g + L*96, ln2_b + L*96,
            w1T_b + (size_t)L*384*96, ff1_b + L*384,
            w2T_b + (size_t)L*96*384, ff2_b + L*96);
    }
    out_kernel<<<dim3(196, 16), 256, 0, stream>>>(xp, (float*)d_out);
}